// Round 1
// baseline (4927.578 us; speedup 1.0000x reference)
//
#include <hip/hip_runtime.h>
#include <math.h>

// ---------------------------------------------------------------------------
// DARM_43267500540057: trunk (head conv + 4x conv3x3+relu + 2x SE + tail conv)
// feeding a dynamic-filter layer with 72 fixed 5x5 basis kernels.
// Round 1: correct fp32 baseline. Direct conv, 32x32x8cout tiles, LDS staged.
// Dynamic filter fused: e[25] = sum_k wgt_k * basis_k, applied with reflect pad
// (avoids 1.36 GB x_com materialization).
// ---------------------------------------------------------------------------

#define HW 128
#define HW2 16384  // 128*128

// Generic 3x3 conv, pad=1. in: [B,Cin,128,128], w: [Cout,Cin,3,3], out: [B,Cout,128,128].
// Optional per-(b,cin) input scale (SE fusion), optional relu, bias always.
// Block: 256 threads = 16x16; each thread does pixels (2ty, tx), (2ty, tx+16),
// (2ty+1, tx), (2ty+1, tx+16) for 8 consecutive couts.
__global__ __launch_bounds__(256) void conv3x3_kernel(
    const float* __restrict__ in, const float* __restrict__ w,
    const float* __restrict__ bias, const float* __restrict__ scale,
    float* __restrict__ out, int Cin, int Cout, int do_relu)
{
    __shared__ float wlds[128 * 9 * 8];   // [cin][tap][co8] — max Cin=128
    __shared__ float tile[34 * 34];       // input tile with 1-halo

    const int tid    = threadIdx.x;
    const int cog    = blockIdx.y;        // cout group of 8
    const int b      = blockIdx.z;
    const int tile_y = (blockIdx.x >> 2) * 32;
    const int tile_x = (blockIdx.x & 3) * 32;

    // Preload all weights for this block into LDS, layout [(ci*9+tap)*8 + co].
    // Note dst index == idx by construction.
    const int wcount = Cin * 72;  // Cin*9*8
    for (int idx = tid; idx < wcount; idx += 256) {
        int co   = idx & 7;
        int rest = idx >> 3;
        int tap  = rest % 9;
        int ci   = rest / 9;
        int gco  = cog * 8 + co;
        wlds[idx] = w[(gco * Cin + ci) * 9 + tap];
    }

    const int ty = tid >> 4;      // 0..15
    const int tx = tid & 15;      // 0..15
    const int py = ty * 2;        // pixel rows py, py+1 within tile

    float acc[2][2][8];
    #pragma unroll
    for (int r = 0; r < 2; ++r)
        #pragma unroll
        for (int h = 0; h < 2; ++h)
            #pragma unroll
            for (int co = 0; co < 8; ++co) acc[r][h][co] = 0.f;

    for (int ci = 0; ci < Cin; ++ci) {
        __syncthreads();  // protect tile (and wlds on first iter) across iters
        const float* inch = in + ((size_t)(b * Cin + ci) << 14);
        const float sc = scale ? scale[b * Cin + ci] : 1.0f;
        for (int idx = tid; idx < 34 * 34; idx += 256) {
            int r  = idx / 34;
            int c  = idx - r * 34;
            int gy = tile_y - 1 + r;
            int gx = tile_x - 1 + c;
            float v = 0.f;
            if ((unsigned)gy < 128u && (unsigned)gx < 128u)
                v = inch[(gy << 7) + gx] * sc;
            tile[idx] = v;
        }
        __syncthreads();

        const float* wl = wlds + ci * 72;
        #pragma unroll
        for (int ky = 0; ky < 3; ++ky) {
            #pragma unroll
            for (int kx = 0; kx < 3; ++kx) {
                const float* wp = wl + (ky * 3 + kx) * 8;
                float i00 = tile[(py + ky) * 34 + tx + kx];
                float i01 = tile[(py + ky) * 34 + tx + 16 + kx];
                float i10 = tile[(py + 1 + ky) * 34 + tx + kx];
                float i11 = tile[(py + 1 + ky) * 34 + tx + 16 + kx];
                #pragma unroll
                for (int co = 0; co < 8; ++co) {
                    float wv = wp[co];  // wave-uniform broadcast
                    acc[0][0][co] += i00 * wv;
                    acc[0][1][co] += i01 * wv;
                    acc[1][0][co] += i10 * wv;
                    acc[1][1][co] += i11 * wv;
                }
            }
        }
    }

    #pragma unroll
    for (int co = 0; co < 8; ++co) {
        int gco = cog * 8 + co;
        float bv = bias[gco];
        float* op = out + ((size_t)(b * Cout + gco) << 14);
        #pragma unroll
        for (int r = 0; r < 2; ++r) {
            #pragma unroll
            for (int h = 0; h < 2; ++h) {
                float v = acc[r][h][co] + bv;
                if (do_relu) v = fmaxf(v, 0.f);
                op[(tile_y + py + r) * 128 + tile_x + tx + h * 16] = v;
            }
        }
    }
}

// Global average pool over H,W per (b,c). grid = B*C blocks.
__global__ __launch_bounds__(256) void mean_kernel(
    const float* __restrict__ f, float* __restrict__ mean)
{
    const int bc = blockIdx.x;
    const float* p = f + ((size_t)bc << 14);
    float s = 0.f;
    for (int i = threadIdx.x; i < HW2; i += 256) s += p[i];
    #pragma unroll
    for (int off = 32; off > 0; off >>= 1) s += __shfl_down(s, off, 64);
    __shared__ float wsum[4];
    int lane = threadIdx.x & 63, wv = threadIdx.x >> 6;
    if (lane == 0) wsum[wv] = s;
    __syncthreads();
    if (threadIdx.x == 0)
        mean[bc] = (wsum[0] + wsum[1] + wsum[2] + wsum[3]) * (1.f / 16384.f);
}

// SE FC chain: scale[b,c] = sigmoid(b2[c] + sum_s w2[c,s]*relu(b1[s]+sum_j w1[s,j]*mean[b,j]))
// grid = B blocks, 128 threads.
__global__ __launch_bounds__(128) void se_kernel(
    const float* __restrict__ mean, const float* __restrict__ w1,
    const float* __restrict__ b1, const float* __restrict__ w2,
    const float* __restrict__ b2, float* __restrict__ scale)
{
    const int b = blockIdx.x;
    const int c = threadIdx.x;
    __shared__ float h1[8];
    if (c < 8) {
        float s = b1[c];
        for (int j = 0; j < 128; ++j) s += w1[c * 128 + j] * mean[b * 128 + j];
        h1[c] = fmaxf(s, 0.f);
    }
    __syncthreads();
    float s = b2[c];
    #pragma unroll
    for (int j = 0; j < 8; ++j) s += w2[c * 8 + j] * h1[j];
    scale[b * 128 + c] = 1.f / (1.f + expf(-s));
}

// Fused dynamic filter: per pixel build e[25] = sum_k wgt[k]*basis[k], then
// apply to 3 channels of x with reflect(2) padding. grid = B*H*W/256.
__global__ __launch_bounds__(256) void dynfilter_kernel(
    const float* __restrict__ x, const float* __restrict__ wgt,
    const float* __restrict__ kern, float* __restrict__ out)
{
    const int gid = blockIdx.x * 256 + threadIdx.x;  // 0 .. 8*16384-1
    const int b   = gid >> 14;
    const int pix = gid & 16383;
    const int h   = pix >> 7;
    const int w   = pix & 127;

    const float* wp = wgt + (size_t)b * 72 * HW2 + pix;
    float e[25];
    #pragma unroll
    for (int i = 0; i < 25; ++i) e[i] = 0.f;
    for (int k = 0; k < 72; ++k) {
        float wk = wp[(size_t)k * HW2];
        #pragma unroll
        for (int i = 0; i < 25; ++i) e[i] += wk * kern[k * 25 + i];  // kern uniform -> s_load
    }

    // reflect-pad indices (jnp.pad 'reflect': -1 -> 1, 128 -> 126)
    int yy[5], xx[5];
    #pragma unroll
    for (int d = 0; d < 5; ++d) {
        int y = h - 2 + d;
        yy[d] = y < 0 ? -y : (y > 127 ? 254 - y : y);
        int xv = w - 2 + d;
        xx[d] = xv < 0 ? -xv : (xv > 127 ? 254 - xv : xv);
    }

    #pragma unroll
    for (int c = 0; c < 3; ++c) {
        const float* xc = x + ((size_t)(b * 3 + c) << 14);
        float s = 0.f;
        #pragma unroll
        for (int dy = 0; dy < 5; ++dy) {
            #pragma unroll
            for (int dx = 0; dx < 5; ++dx)
                s += e[dy * 5 + dx] * xc[yy[dy] * 128 + xx[dx]];
        }
        out[((size_t)(b * 3 + c) << 14) + pix] = s;
    }
}

extern "C" void kernel_launch(void* const* d_in, const int* in_sizes, int n_in,
                              void* d_out, int out_size, void* d_ws, size_t ws_size,
                              hipStream_t stream)
{
    const float* x      = (const float*)d_in[0];
    const float* w_head = (const float*)d_in[1];
    const float* b_head = (const float*)d_in[2];
    const float* w_h1a  = (const float*)d_in[3];
    const float* b_h1a  = (const float*)d_in[4];
    const float* w_h1b  = (const float*)d_in[5];
    const float* b_h1b  = (const float*)d_in[6];
    const float* du1_w1 = (const float*)d_in[7];
    const float* du1_b1 = (const float*)d_in[8];
    const float* du1_w2 = (const float*)d_in[9];
    const float* du1_b2 = (const float*)d_in[10];
    const float* w_h2a  = (const float*)d_in[11];
    const float* b_h2a  = (const float*)d_in[12];
    const float* w_h2b  = (const float*)d_in[13];
    const float* b_h2b  = (const float*)d_in[14];
    const float* du2_w1 = (const float*)d_in[15];
    const float* du2_b1 = (const float*)d_in[16];
    const float* du2_w2 = (const float*)d_in[17];
    const float* du2_b2 = (const float*)d_in[18];
    const float* w_tail = (const float*)d_in[19];
    const float* b_tail = (const float*)d_in[20];
    const float* kern   = (const float*)d_in[21];
    float* out = (float*)d_out;

    const size_t FEAT = (size_t)8 * 128 * HW2;  // 16,777,216 floats = 64 MB
    float* buf0   = (float*)d_ws;
    float* buf1   = buf0 + FEAT;
    float* meanb  = buf1 + FEAT;
    float* scaleb = meanb + 1024;

    dim3 blk(256);
    auto conv = [&](const float* in, const float* w, const float* bias,
                    const float* scale, float* o, int Cin, int Cout, int relu) {
        dim3 grid(16, Cout / 8, 8);
        hipLaunchKernelGGL(conv3x3_kernel, grid, blk, 0, stream,
                           in, w, bias, scale, o, Cin, Cout, relu);
    };

    // trunk
    conv(x,    w_head, b_head, nullptr, buf0, 3,   128, 0);   // head (no relu)
    conv(buf0, w_h1a,  b_h1a,  nullptr, buf1, 128, 128, 1);
    conv(buf1, w_h1b,  b_h1b,  nullptr, buf0, 128, 128, 1);
    mean_kernel<<<1024, 256, 0, stream>>>(buf0, meanb);
    se_kernel<<<8, 128, 0, stream>>>(meanb, du1_w1, du1_b1, du1_w2, du1_b2, scaleb);
    conv(buf0, w_h2a,  b_h2a,  scaleb,  buf1, 128, 128, 1);   // SE1 fused into input
    conv(buf1, w_h2b,  b_h2b,  nullptr, buf0, 128, 128, 1);
    mean_kernel<<<1024, 256, 0, stream>>>(buf0, meanb);
    se_kernel<<<8, 128, 0, stream>>>(meanb, du2_w1, du2_b1, du2_w2, du2_b2, scaleb);
    conv(buf0, w_tail, b_tail, scaleb,  buf1, 128, 72, 0);    // SE2 fused into tail
    // dynamic filter (fused x_com + weighted sum)
    dynfilter_kernel<<<512, 256, 0, stream>>>(x, buf1, kern, out);
}

// Round 2
// 1032.825 us; speedup vs baseline: 4.7710x; 4.7710x over previous
//
#include <hip/hip_runtime.h>
#include <math.h>

// ---------------------------------------------------------------------------
// R2: bf16 MFMA implicit-GEMM convs (NHWC bf16 features, [tap][co][ci] bf16
// weights), fp32 head conv -> NHWC bf16, SE as mean+FC+in-place scale,
// templated NT for tail (Cout 72 padded to 80), bf16 wgt into dynfilter.
// ---------------------------------------------------------------------------

typedef __attribute__((ext_vector_type(8))) short bf16x8;
typedef __attribute__((ext_vector_type(4))) float f32x4;

__device__ inline float bf2f(unsigned short u) {
    unsigned v = ((unsigned)u) << 16;
    return __builtin_bit_cast(float, v);
}
__device__ inline unsigned short f2bf(float f) {
    unsigned u = __builtin_bit_cast(unsigned, f);
    u += 0x7FFF + ((u >> 16) & 1);   // RNE
    return (unsigned short)(u >> 16);
}

// ---------------- head conv: fp32 NCHW (Cin=3) -> NHWC bf16 (C=128) ---------
__global__ __launch_bounds__(256) void head_conv(
    const float* __restrict__ x, const float* __restrict__ w,
    const float* __restrict__ bias, unsigned short* __restrict__ out)
{
    __shared__ float wlds[216];          // [ci][tap][co8]
    __shared__ float tile[3][34 * 34];
    const int tid = threadIdx.x, cog = blockIdx.y, b = blockIdx.z;
    const int tile_y = (blockIdx.x >> 2) * 32, tile_x = (blockIdx.x & 3) * 32;

    if (tid < 216) {
        int co = tid & 7, rest = tid >> 3, tap = rest % 9, ci = rest / 9;
        wlds[tid] = w[((cog * 8 + co) * 3 + ci) * 9 + tap];
    }
    for (int idx = tid; idx < 3 * 34 * 34; idx += 256) {
        int ci = idx / 1156, rem = idx - ci * 1156;
        int r = rem / 34, c = rem - r * 34;
        int gy = tile_y - 1 + r, gx = tile_x - 1 + c;
        float v = 0.f;
        if ((unsigned)gy < 128u && (unsigned)gx < 128u)
            v = x[(((size_t)(b * 3 + ci)) << 14) + (gy << 7) + gx];
        tile[ci][rem] = v;
    }
    __syncthreads();

    const int ty = tid >> 4, tx = tid & 15, py = ty * 2;
    float acc[2][2][8];
    #pragma unroll
    for (int r = 0; r < 2; ++r)
        #pragma unroll
        for (int h = 0; h < 2; ++h)
            #pragma unroll
            for (int co = 0; co < 8; ++co) acc[r][h][co] = 0.f;

    #pragma unroll
    for (int ci = 0; ci < 3; ++ci) {
        #pragma unroll
        for (int ky = 0; ky < 3; ++ky) {
            #pragma unroll
            for (int kx = 0; kx < 3; ++kx) {
                const float* wp = wlds + (ci * 9 + ky * 3 + kx) * 8;
                float i00 = tile[ci][(py + ky) * 34 + tx + kx];
                float i01 = tile[ci][(py + ky) * 34 + tx + 16 + kx];
                float i10 = tile[ci][(py + 1 + ky) * 34 + tx + kx];
                float i11 = tile[ci][(py + 1 + ky) * 34 + tx + 16 + kx];
                #pragma unroll
                for (int co = 0; co < 8; ++co) {
                    float wv = wp[co];
                    acc[0][0][co] += i00 * wv;
                    acc[0][1][co] += i01 * wv;
                    acc[1][0][co] += i10 * wv;
                    acc[1][1][co] += i11 * wv;
                }
            }
        }
    }

    #pragma unroll
    for (int r = 0; r < 2; ++r) {
        #pragma unroll
        for (int h = 0; h < 2; ++h) {
            int gy = tile_y + py + r, gx = tile_x + tx + h * 16;
            bf16x8 pv;
            #pragma unroll
            for (int co = 0; co < 8; ++co)
                pv[co] = (short)f2bf(acc[r][h][co] + bias[cog * 8 + co]);
            *(bf16x8*)(out + (((((size_t)b << 14) + gy * 128 + gx)) << 7) + cog * 8) = pv;
        }
    }
}

// ---------------- main conv: implicit GEMM, bf16 MFMA -----------------------
// in: NHWC bf16 [8][16384][128]; wT: [9][Coutp][128] bf16; out NHWC [..][Coutp]
// block: 8 rows x 16 cols of pixels, 4 waves split rows (2 each), N = NT*16.
template <int NT>
__global__ __launch_bounds__(256, 2) void conv_mfma(
    const unsigned short* __restrict__ in, const unsigned short* __restrict__ wT,
    const float* __restrict__ bias, unsigned short* __restrict__ out,
    int Coutp, int Cout, int relu)
{
    __shared__ unsigned short lds[10 * 18 * 40];  // pixel stride 40 ushort (80B)
    const int tid = threadIdx.x;
    const int b = blockIdx.y;
    const int row0 = (blockIdx.x >> 3) * 8;
    const int col0 = (blockIdx.x & 7) * 16;
    const int l = tid & 63, wv = tid >> 6;
    const int li = l & 15, lq = l >> 4;
    const size_t inb = ((size_t)b) << 14;

    f32x4 acc[2][NT];
    #pragma unroll
    for (int lm = 0; lm < 2; ++lm)
        #pragma unroll
        for (int nt = 0; nt < NT; ++nt)
            acc[lm][nt] = (f32x4){0.f, 0.f, 0.f, 0.f};

    for (int cc = 0; cc < 4; ++cc) {  // 32-ci chunks
        __syncthreads();
        for (int u = tid; u < 720; u += 256) {
            int px = u >> 2, part = u & 3;
            int hr = px / 18, hc = px - hr * 18;
            int gy = row0 - 1 + hr, gx = col0 - 1 + hc;
            bf16x8 v = {0, 0, 0, 0, 0, 0, 0, 0};
            if ((unsigned)gy < 128u && (unsigned)gx < 128u)
                v = *(const bf16x8*)(in + ((inb + (gy << 7) + gx) << 7) + cc * 32 + part * 8);
            *(bf16x8*)(lds + px * 40 + part * 8) = v;
        }
        __syncthreads();

        #pragma unroll
        for (int ky = 0; ky < 3; ++ky) {
            #pragma unroll
            for (int kx = 0; kx < 3; ++kx) {
                bf16x8 bf[NT];
                const unsigned short* wb =
                    wT + ((size_t)((ky * 3 + kx) * Coutp + li)) * 128 + cc * 32 + lq * 8;
                #pragma unroll
                for (int nt = 0; nt < NT; ++nt)
                    bf[nt] = *(const bf16x8*)(wb + nt * 16 * 128);
                #pragma unroll
                for (int lm = 0; lm < 2; ++lm) {
                    int m = wv * 2 + lm;
                    bf16x8 af = *(const bf16x8*)(lds + ((m + ky) * 18 + (li + kx)) * 40 + lq * 8);
                    #pragma unroll
                    for (int nt = 0; nt < NT; ++nt)
                        acc[lm][nt] = __builtin_amdgcn_mfma_f32_16x16x32_bf16(
                            af, bf[nt], acc[lm][nt], 0, 0, 0);
                }
            }
        }
    }

    float bv[NT];
    #pragma unroll
    for (int nt = 0; nt < NT; ++nt) {
        int co = nt * 16 + li;
        bv[nt] = (co < Cout) ? bias[co] : 0.f;
    }
    #pragma unroll
    for (int lm = 0; lm < 2; ++lm) {
        int row = row0 + wv * 2 + lm;
        #pragma unroll
        for (int r = 0; r < 4; ++r) {
            int col = col0 + lq * 4 + r;
            size_t pbase = (inb + row * 128 + col) * (size_t)Coutp;
            #pragma unroll
            for (int nt = 0; nt < NT; ++nt) {
                float v = acc[lm][nt][r] + bv[nt];
                if (relu) v = fmaxf(v, 0.f);
                out[pbase + nt * 16 + li] = f2bf(v);
            }
        }
    }
}

// ---------------- weight transform: [Co][128][3][3] f32 -> [9][Coutp][128] bf16
__global__ __launch_bounds__(256) void wtrans(
    const float* __restrict__ w, unsigned short* __restrict__ wT, int Co, int Coutp)
{
    int idx = blockIdx.x * 256 + threadIdx.x;
    int total = 9 * Coutp * 128;
    if (idx >= total) return;
    int ci = idx & 127, r = idx >> 7;
    int co = r % Coutp, tap = r / Coutp;
    float v = (co < Co) ? w[((size_t)(co * 128 + ci)) * 9 + tap] : 0.f;
    wT[idx] = f2bf(v);
}

// ---------------- SE: mean over pixels (NHWC bf16) --------------------------
__global__ __launch_bounds__(256) void mean_nhwc(
    const unsigned short* __restrict__ f, float* __restrict__ meanb)
{
    int b = blockIdx.x >> 5, slab = blockIdx.x & 31;
    int ci = threadIdx.x & 127, half = threadIdx.x >> 7;
    size_t base = (((size_t)b) << 14) + slab * 512;
    float s = 0.f;
    for (int p = half; p < 512; p += 2)
        s += bf2f(f[((base + p) << 7) + ci]);
    __shared__ float tmp[128];
    if (half) tmp[ci] = s;
    __syncthreads();
    if (!half) atomicAdd(&meanb[b * 128 + ci], s + tmp[ci]);
}

__global__ __launch_bounds__(128) void se_kernel(
    const float* __restrict__ meanb, const float* __restrict__ w1,
    const float* __restrict__ b1, const float* __restrict__ w2,
    const float* __restrict__ b2, float* __restrict__ scale)
{
    const int b = blockIdx.x, c = threadIdx.x;
    __shared__ float h1[8];
    if (c < 8) {
        float s = 0.f;
        for (int j = 0; j < 128; ++j) s += w1[c * 128 + j] * meanb[b * 128 + j];
        h1[c] = fmaxf(s * (1.f / 16384.f) + b1[c], 0.f);
    }
    __syncthreads();
    float s = b2[c];
    #pragma unroll
    for (int j = 0; j < 8; ++j) s += w2[c * 8 + j] * h1[j];
    scale[b * 128 + c] = 1.f / (1.f + expf(-s));
}

__global__ __launch_bounds__(256) void se_apply(
    unsigned short* __restrict__ f, const float* __restrict__ scale)
{
    int u = blockIdx.x * 256 + threadIdx.x;   // 8*16384*16 units of 8 ci
    int b = u >> 18;
    int rest = u & 262143;
    int px = rest >> 4, grp = rest & 15;
    size_t a = ((((size_t)b << 14) + px) << 7) + grp * 8;
    bf16x8 v = *(bf16x8*)(f + a);
    const float* sp = scale + b * 128 + grp * 8;
    #pragma unroll
    for (int j = 0; j < 8; ++j)
        v[j] = (short)f2bf(bf2f((unsigned short)v[j]) * sp[j]);
    *(bf16x8*)(f + a) = v;
}

// ---------------- dynamic filter (wgt bf16 NHWC stride 80) ------------------
__global__ __launch_bounds__(256) void dynfilter(
    const float* __restrict__ x, const unsigned short* __restrict__ wgt,
    const float* __restrict__ kern, float* __restrict__ out)
{
    const int gid = blockIdx.x * 256 + threadIdx.x;  // b*16384 + pix
    const int pix = gid & 16383;
    const int b = gid >> 14;
    const int h = pix >> 7, w = pix & 127;

    const unsigned short* wp = wgt + (size_t)gid * 80;
    float e[25];
    #pragma unroll
    for (int i = 0; i < 25; ++i) e[i] = 0.f;
    #pragma unroll
    for (int k8 = 0; k8 < 9; ++k8) {
        bf16x8 wv8 = *(const bf16x8*)(wp + k8 * 8);
        #pragma unroll
        for (int j = 0; j < 8; ++j) {
            float wk = bf2f((unsigned short)wv8[j]);
            const float* kp = kern + (k8 * 8 + j) * 25;
            #pragma unroll
            for (int i = 0; i < 25; ++i) e[i] += wk * kp[i];
        }
    }

    int yy[5], xx[5];
    #pragma unroll
    for (int d = 0; d < 5; ++d) {
        int y = h - 2 + d;
        yy[d] = y < 0 ? -y : (y > 127 ? 254 - y : y);
        int xv = w - 2 + d;
        xx[d] = xv < 0 ? -xv : (xv > 127 ? 254 - xv : xv);
    }

    #pragma unroll
    for (int c = 0; c < 3; ++c) {
        const float* xc = x + ((size_t)(b * 3 + c) << 14);
        float s = 0.f;
        #pragma unroll
        for (int dy = 0; dy < 5; ++dy)
            #pragma unroll
            for (int dx = 0; dx < 5; ++dx)
                s += e[dy * 5 + dx] * xc[yy[dy] * 128 + xx[dx]];
        out[((size_t)(b * 3 + c) << 14) + pix] = s;
    }
}

// ---------------------------------------------------------------------------
extern "C" void kernel_launch(void* const* d_in, const int* in_sizes, int n_in,
                              void* d_out, int out_size, void* d_ws, size_t ws_size,
                              hipStream_t stream)
{
    const float* x      = (const float*)d_in[0];
    const float* w_head = (const float*)d_in[1];
    const float* b_head = (const float*)d_in[2];
    const float* w_h1a  = (const float*)d_in[3];
    const float* b_h1a  = (const float*)d_in[4];
    const float* w_h1b  = (const float*)d_in[5];
    const float* b_h1b  = (const float*)d_in[6];
    const float* du1_w1 = (const float*)d_in[7];
    const float* du1_b1 = (const float*)d_in[8];
    const float* du1_w2 = (const float*)d_in[9];
    const float* du1_b2 = (const float*)d_in[10];
    const float* w_h2a  = (const float*)d_in[11];
    const float* b_h2a  = (const float*)d_in[12];
    const float* w_h2b  = (const float*)d_in[13];
    const float* b_h2b  = (const float*)d_in[14];
    const float* du2_w1 = (const float*)d_in[15];
    const float* du2_b1 = (const float*)d_in[16];
    const float* du2_w2 = (const float*)d_in[17];
    const float* du2_b2 = (const float*)d_in[18];
    const float* w_tail = (const float*)d_in[19];
    const float* b_tail = (const float*)d_in[20];
    const float* kern   = (const float*)d_in[21];
    float* out = (float*)d_out;

    unsigned short* fb0  = (unsigned short*)d_ws;        // 16,777,216 elems
    unsigned short* fb1  = fb0 + 16777216;
    unsigned short* wgtb = fb1 + 16777216;               // 8*16384*80
    unsigned short* wt1  = wgtb + 10485760;              // 9*128*128 each
    unsigned short* wt2  = wt1 + 147456;
    unsigned short* wt3  = wt2 + 147456;
    unsigned short* wt4  = wt3 + 147456;
    unsigned short* wtt  = wt4 + 147456;                 // 9*80*128
    float* meanb  = (float*)(wtt + 92160);
    float* scaleb = meanb + 1024;

    dim3 blk(256);
    // weight transforms
    wtrans<<<576, blk, 0, stream>>>(w_h1a, wt1, 128, 128);
    wtrans<<<576, blk, 0, stream>>>(w_h1b, wt2, 128, 128);
    wtrans<<<576, blk, 0, stream>>>(w_h2a, wt3, 128, 128);
    wtrans<<<576, blk, 0, stream>>>(w_h2b, wt4, 128, 128);
    wtrans<<<360, blk, 0, stream>>>(w_tail, wtt, 72, 80);

    head_conv<<<dim3(16, 16, 8), blk, 0, stream>>>(x, w_head, b_head, fb0);

    dim3 cgrid(128, 8);
    conv_mfma<8><<<cgrid, blk, 0, stream>>>(fb0, wt1, b_h1a, fb1, 128, 128, 1);
    conv_mfma<8><<<cgrid, blk, 0, stream>>>(fb1, wt2, b_h1b, fb0, 128, 128, 1);

    hipMemsetAsync(meanb, 0, 4096, stream);
    mean_nhwc<<<256, blk, 0, stream>>>(fb0, meanb);
    se_kernel<<<8, 128, 0, stream>>>(meanb, du1_w1, du1_b1, du1_w2, du1_b2, scaleb);
    se_apply<<<8192, blk, 0, stream>>>(fb0, scaleb);

    conv_mfma<8><<<cgrid, blk, 0, stream>>>(fb0, wt3, b_h2a, fb1, 128, 128, 1);
    conv_mfma<8><<<cgrid, blk, 0, stream>>>(fb1, wt4, b_h2b, fb0, 128, 128, 1);

    hipMemsetAsync(meanb, 0, 4096, stream);
    mean_nhwc<<<256, blk, 0, stream>>>(fb0, meanb);
    se_kernel<<<8, 128, 0, stream>>>(meanb, du2_w1, du2_b1, du2_w2, du2_b2, scaleb);
    se_apply<<<8192, blk, 0, stream>>>(fb0, scaleb);

    conv_mfma<5><<<cgrid, blk, 0, stream>>>(fb0, wtt, b_tail, wgtb, 80, 72, 0);

    dynfilter<<<512, blk, 0, stream>>>(x, wgtb, kern, out);
}

// Round 3
// 733.625 us; speedup vs baseline: 6.7168x; 1.4078x over previous
//
#include <hip/hip_runtime.h>
#include <math.h>

// ---------------------------------------------------------------------------
// R3: conv_mfma restructured — full-channel A tile staged once (1 barrier),
// weights repacked [tap*4+kc][co][32ch] for contiguous 1KB wave-reads,
// register double-buffered B prefetch, SE folded into per-batch scaled weights.
// ---------------------------------------------------------------------------

typedef __attribute__((ext_vector_type(8))) short bf16x8;
typedef __attribute__((ext_vector_type(4))) float f32x4;

__device__ inline float bf2f(unsigned short u) {
    unsigned v = ((unsigned)u) << 16;
    return __builtin_bit_cast(float, v);
}
__device__ inline unsigned short f2bf(float f) {
    unsigned u = __builtin_bit_cast(unsigned, f);
    u += 0x7FFF + ((u >> 16) & 1);   // RNE
    return (unsigned short)(u >> 16);
}

// ---------------- head conv: fp32 NCHW (Cin=3) -> NHWC bf16 (C=128) ---------
__global__ __launch_bounds__(256) void head_conv(
    const float* __restrict__ x, const float* __restrict__ w,
    const float* __restrict__ bias, unsigned short* __restrict__ out)
{
    __shared__ float wlds[216];          // [ci][tap][co8]
    __shared__ float tile[3][34 * 34];
    const int tid = threadIdx.x, cog = blockIdx.y, b = blockIdx.z;
    const int tile_y = (blockIdx.x >> 2) * 32, tile_x = (blockIdx.x & 3) * 32;

    if (tid < 216) {
        int co = tid & 7, rest = tid >> 3, tap = rest % 9, ci = rest / 9;
        wlds[tid] = w[((cog * 8 + co) * 3 + ci) * 9 + tap];
    }
    for (int idx = tid; idx < 3 * 34 * 34; idx += 256) {
        int ci = idx / 1156, rem = idx - ci * 1156;
        int r = rem / 34, c = rem - r * 34;
        int gy = tile_y - 1 + r, gx = tile_x - 1 + c;
        float v = 0.f;
        if ((unsigned)gy < 128u && (unsigned)gx < 128u)
            v = x[(((size_t)(b * 3 + ci)) << 14) + (gy << 7) + gx];
        tile[ci][rem] = v;
    }
    __syncthreads();

    const int ty = tid >> 4, tx = tid & 15, py = ty * 2;
    float acc[2][2][8];
    #pragma unroll
    for (int r = 0; r < 2; ++r)
        #pragma unroll
        for (int h = 0; h < 2; ++h)
            #pragma unroll
            for (int co = 0; co < 8; ++co) acc[r][h][co] = 0.f;

    #pragma unroll
    for (int ci = 0; ci < 3; ++ci) {
        #pragma unroll
        for (int ky = 0; ky < 3; ++ky) {
            #pragma unroll
            for (int kx = 0; kx < 3; ++kx) {
                const float* wp = wlds + (ci * 9 + ky * 3 + kx) * 8;
                float i00 = tile[ci][(py + ky) * 34 + tx + kx];
                float i01 = tile[ci][(py + ky) * 34 + tx + 16 + kx];
                float i10 = tile[ci][(py + 1 + ky) * 34 + tx + kx];
                float i11 = tile[ci][(py + 1 + ky) * 34 + tx + 16 + kx];
                #pragma unroll
                for (int co = 0; co < 8; ++co) {
                    float wv = wp[co];
                    acc[0][0][co] += i00 * wv;
                    acc[0][1][co] += i01 * wv;
                    acc[1][0][co] += i10 * wv;
                    acc[1][1][co] += i11 * wv;
                }
            }
        }
    }

    #pragma unroll
    for (int r = 0; r < 2; ++r) {
        #pragma unroll
        for (int h = 0; h < 2; ++h) {
            int gy = tile_y + py + r, gx = tile_x + tx + h * 16;
            bf16x8 pv;
            #pragma unroll
            for (int co = 0; co < 8; ++co)
                pv[co] = (short)f2bf(acc[r][h][co] + bias[cog * 8 + co]);
            *(bf16x8*)(out + (((((size_t)b << 14) + gy * 128 + gx)) << 7) + cog * 8) = pv;
        }
    }
}

// ---------------- main conv: implicit GEMM, bf16 MFMA -----------------------
// in: NHWC bf16 [8][16384][128]; wT: [tap*4+kc][Coutp][32] bf16 (+ per-batch
// copies when wstride != 0); out NHWC [..][Coutp].
// Block: 8 rows x 16 cols pixels, full 128-ch tile staged once, 1 barrier,
// 36-slice K loop with register double-buffered B.
template <int NT>
__global__ __launch_bounds__(256, 3) void conv_mfma(
    const unsigned short* __restrict__ in, const unsigned short* __restrict__ wT,
    size_t wstride, const float* __restrict__ bias, unsigned short* __restrict__ out,
    int Coutp, int Cout, int relu)
{
    __shared__ unsigned short lds[180 * 136];  // 10x18 px, stride 136 ush (272B)
    const int tid = threadIdx.x;
    const int b = blockIdx.y;
    const int row0 = (blockIdx.x >> 3) * 8;
    const int col0 = (blockIdx.x & 7) * 16;
    const int l = tid & 63, wv = tid >> 6;
    const int li = l & 15, lq = l >> 4;
    const size_t inb = ((size_t)b) << 14;
    const unsigned short* wbase = wT + (size_t)b * wstride;

    // stage full 10x18x128ch tile (zero-filled halo), one barrier
    for (int u = tid; u < 2880; u += 256) {
        int px = u >> 4, part = u & 15;
        int hr = px / 18, hc = px - hr * 18;
        int gy = row0 - 1 + hr, gx = col0 - 1 + hc;
        bf16x8 v = {0, 0, 0, 0, 0, 0, 0, 0};
        if ((unsigned)gy < 128u && (unsigned)gx < 128u)
            v = *(const bf16x8*)(in + ((inb + (gy << 7) + gx) << 7) + part * 8);
        *(bf16x8*)(lds + px * 136 + part * 8) = v;
    }
    __syncthreads();

    f32x4 acc[2][NT];
    #pragma unroll
    for (int lm = 0; lm < 2; ++lm)
        #pragma unroll
        for (int nt = 0; nt < NT; ++nt)
            acc[lm][nt] = (f32x4){0.f, 0.f, 0.f, 0.f};

    auto loadB = [&](bf16x8 (&dst)[NT], int idx) {
        const unsigned short* p = wbase + (size_t)idx * (Coutp * 32) + li * 32 + lq * 8;
        #pragma unroll
        for (int nt = 0; nt < NT; ++nt)
            dst[nt] = *(const bf16x8*)(p + nt * 512);
    };
    auto compute = [&](bf16x8 (&bf)[NT], int idx) {
        int tap = idx >> 2, kc = idx & 3;
        int ky = tap / 3, kx = tap - ky * 3;
        int coff = kc * 32 + lq * 8;
        #pragma unroll
        for (int lm = 0; lm < 2; ++lm) {
            bf16x8 af = *(const bf16x8*)(
                lds + ((wv * 2 + lm + ky) * 18 + li + kx) * 136 + coff);
            #pragma unroll
            for (int nt = 0; nt < NT; ++nt)
                acc[lm][nt] = __builtin_amdgcn_mfma_f32_16x16x32_bf16(
                    af, bf[nt], acc[lm][nt], 0, 0, 0);
        }
    };

    bf16x8 bufA[NT], bufB[NT];
    loadB(bufA, 0);
    #pragma unroll 1
    for (int it = 0; it < 36; it += 2) {
        loadB(bufB, it + 1);
        compute(bufA, it);
        if (it + 2 < 36) loadB(bufA, it + 2);
        compute(bufB, it + 1);
    }

    float bv[NT];
    #pragma unroll
    for (int nt = 0; nt < NT; ++nt) {
        int co = nt * 16 + li;
        bv[nt] = (co < Cout) ? bias[co] : 0.f;
    }
    #pragma unroll
    for (int lm = 0; lm < 2; ++lm) {
        int row = row0 + wv * 2 + lm;
        #pragma unroll
        for (int r = 0; r < 4; ++r) {
            int col = col0 + lq * 4 + r;
            size_t pbase = (inb + row * 128 + col) * (size_t)Coutp;
            #pragma unroll
            for (int nt = 0; nt < NT; ++nt) {
                float v = acc[lm][nt][r] + bv[nt];
                if (relu) v = fmaxf(v, 0.f);
                out[pbase + nt * 16 + li] = f2bf(v);
            }
        }
    }
}

// ---- weight transform: [Co][128][3][3] f32 -> [tap*4+kc][Coutp][32] bf16 ---
__global__ __launch_bounds__(256) void wtrans(
    const float* __restrict__ w, unsigned short* __restrict__ wT, int Co, int Coutp)
{
    int idx = blockIdx.x * 256 + threadIdx.x;
    if (idx >= 9 * 4 * Coutp * 32) return;
    int ch = idx & 31;
    int rest = idx >> 5;          // (tap*4+kc)*Coutp + co
    int co = rest % Coutp;
    int slice = rest / Coutp;
    int kc = slice & 3, tap = slice >> 2;
    float v = (co < Co) ? w[((size_t)(co * 128 + kc * 32 + ch)) * 9 + tap] : 0.f;
    wT[idx] = f2bf(v);
}

// ---- per-batch SE-scaled weight copies: out[b][...] = wT[...] * s[b][ci] ---
__global__ __launch_bounds__(256) void wscale8(
    const unsigned short* __restrict__ wT, const float* __restrict__ scale,
    unsigned short* __restrict__ out, int Coutp)
{
    int r = blockIdx.x * 256 + threadIdx.x;
    int b = blockIdx.y;
    int ch = r & 31;
    int slice = (r >> 5) / Coutp;
    int kc = slice & 3;
    float s = scale[b * 128 + kc * 32 + ch];
    out[(size_t)b * (9 * 4 * Coutp * 32) + r] = f2bf(bf2f(wT[r]) * s);
}

// ---------------- SE: mean over pixels (NHWC bf16) --------------------------
__global__ __launch_bounds__(256) void mean_nhwc(
    const unsigned short* __restrict__ f, float* __restrict__ meanb)
{
    int b = blockIdx.x >> 5, slab = blockIdx.x & 31;
    int ci = threadIdx.x & 127, half = threadIdx.x >> 7;
    size_t base = (((size_t)b) << 14) + slab * 512;
    float s = 0.f;
    for (int p = half; p < 512; p += 2)
        s += bf2f(f[((base + p) << 7) + ci]);
    __shared__ float tmp[128];
    if (half) tmp[ci] = s;
    __syncthreads();
    if (!half) atomicAdd(&meanb[b * 128 + ci], s + tmp[ci]);
}

__global__ __launch_bounds__(128) void se_kernel(
    const float* __restrict__ meanb, const float* __restrict__ w1,
    const float* __restrict__ b1, const float* __restrict__ w2,
    const float* __restrict__ b2, float* __restrict__ scale)
{
    const int b = blockIdx.x, c = threadIdx.x;
    __shared__ float h1[8];
    if (c < 8) {
        float s = 0.f;
        for (int j = 0; j < 128; ++j) s += w1[c * 128 + j] * meanb[b * 128 + j];
        h1[c] = fmaxf(s * (1.f / 16384.f) + b1[c], 0.f);
    }
    __syncthreads();
    float s = b2[c];
    #pragma unroll
    for (int j = 0; j < 8; ++j) s += w2[c * 8 + j] * h1[j];
    scale[b * 128 + c] = 1.f / (1.f + expf(-s));
}

// ---------------- dynamic filter (wgt bf16 NHWC stride 80) ------------------
__global__ __launch_bounds__(256) void dynfilter(
    const float* __restrict__ x, const unsigned short* __restrict__ wgt,
    const float* __restrict__ kern, float* __restrict__ out)
{
    const int gid = blockIdx.x * 256 + threadIdx.x;  // b*16384 + pix
    const int pix = gid & 16383;
    const int b = gid >> 14;
    const int h = pix >> 7, w = pix & 127;

    const unsigned short* wp = wgt + (size_t)gid * 80;
    float e[25];
    #pragma unroll
    for (int i = 0; i < 25; ++i) e[i] = 0.f;
    #pragma unroll
    for (int k8 = 0; k8 < 9; ++k8) {
        bf16x8 wv8 = *(const bf16x8*)(wp + k8 * 8);
        #pragma unroll
        for (int j = 0; j < 8; ++j) {
            float wk = bf2f((unsigned short)wv8[j]);
            const float* kp = kern + (k8 * 8 + j) * 25;
            #pragma unroll
            for (int i = 0; i < 25; ++i) e[i] += wk * kp[i];
        }
    }

    int yy[5], xx[5];
    #pragma unroll
    for (int d = 0; d < 5; ++d) {
        int y = h - 2 + d;
        yy[d] = y < 0 ? -y : (y > 127 ? 254 - y : y);
        int xv = w - 2 + d;
        xx[d] = xv < 0 ? -xv : (xv > 127 ? 254 - xv : xv);
    }

    #pragma unroll
    for (int c = 0; c < 3; ++c) {
        const float* xc = x + ((size_t)(b * 3 + c) << 14);
        float s = 0.f;
        #pragma unroll
        for (int dy = 0; dy < 5; ++dy)
            #pragma unroll
            for (int dx = 0; dx < 5; ++dx)
                s += e[dy * 5 + dx] * xc[yy[dy] * 128 + xx[dx]];
        out[((size_t)(b * 3 + c) << 14) + pix] = s;
    }
}

// ---------------------------------------------------------------------------
extern "C" void kernel_launch(void* const* d_in, const int* in_sizes, int n_in,
                              void* d_out, int out_size, void* d_ws, size_t ws_size,
                              hipStream_t stream)
{
    const float* x      = (const float*)d_in[0];
    const float* w_head = (const float*)d_in[1];
    const float* b_head = (const float*)d_in[2];
    const float* w_h1a  = (const float*)d_in[3];
    const float* b_h1a  = (const float*)d_in[4];
    const float* w_h1b  = (const float*)d_in[5];
    const float* b_h1b  = (const float*)d_in[6];
    const float* du1_w1 = (const float*)d_in[7];
    const float* du1_b1 = (const float*)d_in[8];
    const float* du1_w2 = (const float*)d_in[9];
    const float* du1_b2 = (const float*)d_in[10];
    const float* w_h2a  = (const float*)d_in[11];
    const float* b_h2a  = (const float*)d_in[12];
    const float* w_h2b  = (const float*)d_in[13];
    const float* b_h2b  = (const float*)d_in[14];
    const float* du2_w1 = (const float*)d_in[15];
    const float* du2_b1 = (const float*)d_in[16];
    const float* du2_w2 = (const float*)d_in[17];
    const float* du2_b2 = (const float*)d_in[18];
    const float* w_tail = (const float*)d_in[19];
    const float* b_tail = (const float*)d_in[20];
    const float* kern   = (const float*)d_in[21];
    float* out = (float*)d_out;

    unsigned short* fb0  = (unsigned short*)d_ws;        // 16,777,216 elems
    unsigned short* fb1  = fb0 + 16777216;
    unsigned short* wgtb = fb1 + 16777216;               // 8*16384*80
    unsigned short* wt1  = wgtb + 10485760;              // 9*4*128*32 = 147456 each
    unsigned short* wt2  = wt1 + 147456;
    unsigned short* wt3  = wt2 + 147456;
    unsigned short* wt4  = wt3 + 147456;
    unsigned short* wtt  = wt4 + 147456;                 // 9*4*80*32 = 92160
    unsigned short* wsa  = wtt + 92160;                  // 8x scaled h2a weights
    unsigned short* wst  = wsa + 8 * 147456;             // 8x scaled tail weights
    float* meanb  = (float*)(wst + 8 * 92160);
    float* scaleb = meanb + 1024;

    dim3 blk(256);
    wtrans<<<576, blk, 0, stream>>>(w_h1a, wt1, 128, 128);
    wtrans<<<576, blk, 0, stream>>>(w_h1b, wt2, 128, 128);
    wtrans<<<576, blk, 0, stream>>>(w_h2a, wt3, 128, 128);
    wtrans<<<576, blk, 0, stream>>>(w_h2b, wt4, 128, 128);
    wtrans<<<360, blk, 0, stream>>>(w_tail, wtt, 72, 80);

    head_conv<<<dim3(16, 16, 8), blk, 0, stream>>>(x, w_head, b_head, fb0);

    dim3 cgrid(128, 8);
    conv_mfma<8><<<cgrid, blk, 0, stream>>>(fb0, wt1, 0, b_h1a, fb1, 128, 128, 1);
    conv_mfma<8><<<cgrid, blk, 0, stream>>>(fb1, wt2, 0, b_h1b, fb0, 128, 128, 1);

    hipMemsetAsync(meanb, 0, 4096, stream);
    mean_nhwc<<<256, blk, 0, stream>>>(fb0, meanb);
    se_kernel<<<8, 128, 0, stream>>>(meanb, du1_w1, du1_b1, du1_w2, du1_b2, scaleb);
    wscale8<<<dim3(576, 8), blk, 0, stream>>>(wt3, scaleb, wsa, 128);

    conv_mfma<8><<<cgrid, blk, 0, stream>>>(fb0, wsa, 147456, b_h2a, fb1, 128, 128, 1);
    conv_mfma<8><<<cgrid, blk, 0, stream>>>(fb1, wt4, 0, b_h2b, fb0, 128, 128, 1);

    hipMemsetAsync(meanb, 0, 4096, stream);
    mean_nhwc<<<256, blk, 0, stream>>>(fb0, meanb);
    se_kernel<<<8, 128, 0, stream>>>(meanb, du2_w1, du2_b1, du2_w2, du2_b2, scaleb);
    wscale8<<<dim3(360, 8), blk, 0, stream>>>(wtt, scaleb, wst, 80);

    conv_mfma<5><<<cgrid, blk, 0, stream>>>(fb0, wst, 92160, b_tail, wgtb, 80, 72, 0);

    dynfilter<<<512, blk, 0, stream>>>(x, wgtb, kern, out);
}

// Round 4
// 526.847 us; speedup vs baseline: 9.3530x; 1.3925x over previous
//
#include <hip/hip_runtime.h>
#include <math.h>

// ---------------------------------------------------------------------------
// R4: conv_mfma with lm=4 (4 M-tiles/wave -> 32 MFMA per 8 B-loads), A-tile
// 18x18 px staged in two 64-ch halves (46.6 KB LDS, 2 barriers). dynfilter
// wgt reads routed through LDS for coalescing. SE folded into weights (R3).
// ---------------------------------------------------------------------------

typedef __attribute__((ext_vector_type(8))) short bf16x8;
typedef __attribute__((ext_vector_type(4))) float f32x4;

__device__ inline float bf2f(unsigned short u) {
    unsigned v = ((unsigned)u) << 16;
    return __builtin_bit_cast(float, v);
}
__device__ inline unsigned short f2bf(float f) {
    unsigned u = __builtin_bit_cast(unsigned, f);
    u += 0x7FFF + ((u >> 16) & 1);   // RNE
    return (unsigned short)(u >> 16);
}

// ---------------- head conv: fp32 NCHW (Cin=3) -> NHWC bf16 (C=128) ---------
__global__ __launch_bounds__(256) void head_conv(
    const float* __restrict__ x, const float* __restrict__ w,
    const float* __restrict__ bias, unsigned short* __restrict__ out)
{
    __shared__ float wlds[216];          // [ci][tap][co8]
    __shared__ float tile[3][34 * 34];
    const int tid = threadIdx.x, cog = blockIdx.y, b = blockIdx.z;
    const int tile_y = (blockIdx.x >> 2) * 32, tile_x = (blockIdx.x & 3) * 32;

    if (tid < 216) {
        int co = tid & 7, rest = tid >> 3, tap = rest % 9, ci = rest / 9;
        wlds[tid] = w[((cog * 8 + co) * 3 + ci) * 9 + tap];
    }
    for (int idx = tid; idx < 3 * 34 * 34; idx += 256) {
        int ci = idx / 1156, rem = idx - ci * 1156;
        int r = rem / 34, c = rem - r * 34;
        int gy = tile_y - 1 + r, gx = tile_x - 1 + c;
        float v = 0.f;
        if ((unsigned)gy < 128u && (unsigned)gx < 128u)
            v = x[(((size_t)(b * 3 + ci)) << 14) + (gy << 7) + gx];
        tile[ci][rem] = v;
    }
    __syncthreads();

    const int ty = tid >> 4, tx = tid & 15, py = ty * 2;
    float acc[2][2][8];
    #pragma unroll
    for (int r = 0; r < 2; ++r)
        #pragma unroll
        for (int h = 0; h < 2; ++h)
            #pragma unroll
            for (int co = 0; co < 8; ++co) acc[r][h][co] = 0.f;

    #pragma unroll
    for (int ci = 0; ci < 3; ++ci) {
        #pragma unroll
        for (int ky = 0; ky < 3; ++ky) {
            #pragma unroll
            for (int kx = 0; kx < 3; ++kx) {
                const float* wp = wlds + (ci * 9 + ky * 3 + kx) * 8;
                float i00 = tile[ci][(py + ky) * 34 + tx + kx];
                float i01 = tile[ci][(py + ky) * 34 + tx + 16 + kx];
                float i10 = tile[ci][(py + 1 + ky) * 34 + tx + kx];
                float i11 = tile[ci][(py + 1 + ky) * 34 + tx + 16 + kx];
                #pragma unroll
                for (int co = 0; co < 8; ++co) {
                    float wv = wp[co];
                    acc[0][0][co] += i00 * wv;
                    acc[0][1][co] += i01 * wv;
                    acc[1][0][co] += i10 * wv;
                    acc[1][1][co] += i11 * wv;
                }
            }
        }
    }

    #pragma unroll
    for (int r = 0; r < 2; ++r) {
        #pragma unroll
        for (int h = 0; h < 2; ++h) {
            int gy = tile_y + py + r, gx = tile_x + tx + h * 16;
            bf16x8 pv;
            #pragma unroll
            for (int co = 0; co < 8; ++co)
                pv[co] = (short)f2bf(acc[r][h][co] + bias[cog * 8 + co]);
            *(bf16x8*)(out + (((((size_t)b << 14) + gy * 128 + gx)) << 7) + cog * 8) = pv;
        }
    }
}

// ---------------- main conv: implicit GEMM, bf16 MFMA -----------------------
// in: NHWC bf16 [8][16384][128]; wT: [tap*4+kc][Coutp][32] bf16 (+ per-batch
// copies when wstride != 0); out NHWC [..][Coutp].
// Block: 16x16 px, 4 waves x 4 row-tiles (lm=4), A staged in two 64-ch halves.
template <int NT>
__global__ __launch_bounds__(256, 2) void conv_mfma(
    const unsigned short* __restrict__ in, const unsigned short* __restrict__ wT,
    size_t wstride, const float* __restrict__ bias, unsigned short* __restrict__ out,
    int Coutp, int Cout, int relu)
{
    __shared__ unsigned short lds[324 * 72];  // 18x18 px, 64 ch + 8 pad (144 B/px)
    const int tid = threadIdx.x;
    const int b = blockIdx.y;
    const int row0 = (blockIdx.x >> 3) << 4;
    const int col0 = (blockIdx.x & 7) << 4;
    const int l = tid & 63, wv = tid >> 6;
    const int li = l & 15, lq = l >> 4;
    const size_t inb = ((size_t)b) << 14;
    const unsigned short* wbase = wT + (size_t)b * wstride;

    f32x4 acc[4][NT];
    #pragma unroll
    for (int lm = 0; lm < 4; ++lm)
        #pragma unroll
        for (int nt = 0; nt < NT; ++nt)
            acc[lm][nt] = (f32x4){0.f, 0.f, 0.f, 0.f};

    #pragma unroll 1
    for (int half = 0; half < 2; ++half) {
        __syncthreads();
        for (int u = tid; u < 2592; u += 256) {   // 324 px * 8 parts (64 ch)
            int px = u >> 3, part = u & 7;
            int hr = px / 18, hc = px - hr * 18;
            int gy = row0 - 1 + hr, gx = col0 - 1 + hc;
            bf16x8 v = {0, 0, 0, 0, 0, 0, 0, 0};
            if ((unsigned)gy < 128u && (unsigned)gx < 128u)
                v = *(const bf16x8*)(in + ((inb + (gy << 7) + gx) << 7) + half * 64 + part * 8);
            *(bf16x8*)(lds + px * 72 + part * 8) = v;
        }
        __syncthreads();

        auto loadB = [&](bf16x8 (&dst)[NT], int s) {
            int tap = s >> 1, kcl = s & 1;
            const unsigned short* p = wbase +
                (size_t)(tap * 4 + half * 2 + kcl) * (Coutp * 32) + li * 32 + lq * 8;
            #pragma unroll
            for (int nt = 0; nt < NT; ++nt)
                dst[nt] = *(const bf16x8*)(p + nt * 512);
        };
        auto compute = [&](bf16x8 (&bf)[NT], int s) {
            int tap = s >> 1, kcl = s & 1;
            int ky = tap / 3, kx = tap - ky * 3;
            int coff = kcl * 32 + lq * 8;
            #pragma unroll
            for (int lm = 0; lm < 4; ++lm) {
                bf16x8 af = *(const bf16x8*)(
                    lds + ((wv * 4 + lm + ky) * 18 + li + kx) * 72 + coff);
                #pragma unroll
                for (int nt = 0; nt < NT; ++nt)
                    acc[lm][nt] = __builtin_amdgcn_mfma_f32_16x16x32_bf16(
                        af, bf[nt], acc[lm][nt], 0, 0, 0);
            }
        };

        bf16x8 bufA[NT], bufB[NT];
        loadB(bufA, 0);
        #pragma unroll 1
        for (int it = 0; it < 18; it += 2) {
            loadB(bufB, it + 1);
            compute(bufA, it);
            if (it + 2 < 18) loadB(bufA, it + 2);
            compute(bufB, it + 1);
        }
    }

    float bv[NT];
    #pragma unroll
    for (int nt = 0; nt < NT; ++nt) {
        int co = nt * 16 + li;
        bv[nt] = (co < Cout) ? bias[co] : 0.f;
    }
    #pragma unroll
    for (int lm = 0; lm < 4; ++lm) {
        int row = row0 + wv * 4 + lm;
        #pragma unroll
        for (int r = 0; r < 4; ++r) {
            int col = col0 + lq * 4 + r;
            size_t pbase = (inb + row * 128 + col) * (size_t)Coutp;
            #pragma unroll
            for (int nt = 0; nt < NT; ++nt) {
                float v = acc[lm][nt][r] + bv[nt];
                if (relu) v = fmaxf(v, 0.f);
                out[pbase + nt * 16 + li] = f2bf(v);
            }
        }
    }
}

// ---- weight transform: [Co][128][3][3] f32 -> [tap*4+kc][Coutp][32] bf16 ---
__global__ __launch_bounds__(256) void wtrans(
    const float* __restrict__ w, unsigned short* __restrict__ wT, int Co, int Coutp)
{
    int idx = blockIdx.x * 256 + threadIdx.x;
    if (idx >= 9 * 4 * Coutp * 32) return;
    int ch = idx & 31;
    int rest = idx >> 5;          // (tap*4+kc)*Coutp + co
    int co = rest % Coutp;
    int slice = rest / Coutp;
    int kc = slice & 3, tap = slice >> 2;
    float v = (co < Co) ? w[((size_t)(co * 128 + kc * 32 + ch)) * 9 + tap] : 0.f;
    wT[idx] = f2bf(v);
}

// ---- per-batch SE-scaled weight copies: out[b][...] = wT[...] * s[b][ci] ---
__global__ __launch_bounds__(256) void wscale8(
    const unsigned short* __restrict__ wT, const float* __restrict__ scale,
    unsigned short* __restrict__ out, int Coutp)
{
    int r = blockIdx.x * 256 + threadIdx.x;
    int b = blockIdx.y;
    int ch = r & 31;
    int slice = (r >> 5) / Coutp;
    int kc = slice & 3;
    float s = scale[b * 128 + kc * 32 + ch];
    out[(size_t)b * (9 * 4 * Coutp * 32) + r] = f2bf(bf2f(wT[r]) * s);
}

// ---------------- SE: mean over pixels (NHWC bf16) --------------------------
__global__ __launch_bounds__(256) void mean_nhwc(
    const unsigned short* __restrict__ f, float* __restrict__ meanb)
{
    int b = blockIdx.x >> 5, slab = blockIdx.x & 31;
    int ci = threadIdx.x & 127, half = threadIdx.x >> 7;
    size_t base = (((size_t)b) << 14) + slab * 512;
    float s = 0.f;
    for (int p = half; p < 512; p += 2)
        s += bf2f(f[((base + p) << 7) + ci]);
    __shared__ float tmp[128];
    if (half) tmp[ci] = s;
    __syncthreads();
    if (!half) atomicAdd(&meanb[b * 128 + ci], s + tmp[ci]);
}

__global__ __launch_bounds__(128) void se_kernel(
    const float* __restrict__ meanb, const float* __restrict__ w1,
    const float* __restrict__ b1, const float* __restrict__ w2,
    const float* __restrict__ b2, float* __restrict__ scale)
{
    const int b = blockIdx.x, c = threadIdx.x;
    __shared__ float h1[8];
    if (c < 8) {
        float s = 0.f;
        for (int j = 0; j < 128; ++j) s += w1[c * 128 + j] * meanb[b * 128 + j];
        h1[c] = fmaxf(s * (1.f / 16384.f) + b1[c], 0.f);
    }
    __syncthreads();
    float s = b2[c];
    #pragma unroll
    for (int j = 0; j < 8; ++j) s += w2[c * 8 + j] * h1[j];
    scale[b * 128 + c] = 1.f / (1.f + expf(-s));
}

// ---------------- dynamic filter: wgt staged via LDS for coalescing ---------
__global__ __launch_bounds__(256) void dynfilter(
    const float* __restrict__ x, const unsigned short* __restrict__ wgt,
    const float* __restrict__ kern, float* __restrict__ out)
{
    __shared__ unsigned short wl[256 * 88];   // 256 px, 80 wgt + 8 pad (176 B/px)
    const int blk = blockIdx.x;               // 512 blocks
    const int b = blk >> 6;
    const int px0 = (blk & 63) << 8;

    const unsigned short* src = wgt + ((size_t)b * 16384 + px0) * 80;
    for (int u = threadIdx.x; u < 2560; u += 256) {   // coalesced 16B units
        int px = u / 10, k8 = u - px * 10;
        *(bf16x8*)(wl + px * 88 + k8 * 8) = *(const bf16x8*)(src + u * 8);
    }
    __syncthreads();

    const int pix = px0 + threadIdx.x;
    const int h = pix >> 7, w = pix & 127;
    const unsigned short* rowp = wl + threadIdx.x * 88;

    float e[25];
    #pragma unroll
    for (int i = 0; i < 25; ++i) e[i] = 0.f;
    #pragma unroll
    for (int u8 = 0; u8 < 9; ++u8) {          // 72 = 9*8 exactly
        bf16x8 wv8 = *(const bf16x8*)(rowp + u8 * 8);
        #pragma unroll
        for (int j = 0; j < 8; ++j) {
            float wk = bf2f((unsigned short)wv8[j]);
            const float* kp = kern + (u8 * 8 + j) * 25;   // lane-uniform -> s_load
            #pragma unroll
            for (int i = 0; i < 25; ++i) e[i] += wk * kp[i];
        }
    }

    int yy[5], xx[5];
    #pragma unroll
    for (int d = 0; d < 5; ++d) {
        int y = h - 2 + d;
        yy[d] = y < 0 ? -y : (y > 127 ? 254 - y : y);
        int xv = w - 2 + d;
        xx[d] = xv < 0 ? -xv : (xv > 127 ? 254 - xv : xv);
    }

    #pragma unroll
    for (int c = 0; c < 3; ++c) {
        const float* xc = x + ((size_t)(b * 3 + c) << 14);
        float s = 0.f;
        #pragma unroll
        for (int dy = 0; dy < 5; ++dy)
            #pragma unroll
            for (int dx = 0; dx < 5; ++dx)
                s += e[dy * 5 + dx] * xc[yy[dy] * 128 + xx[dx]];
        out[((size_t)(b * 3 + c) << 14) + pix] = s;
    }
}

// ---------------------------------------------------------------------------
extern "C" void kernel_launch(void* const* d_in, const int* in_sizes, int n_in,
                              void* d_out, int out_size, void* d_ws, size_t ws_size,
                              hipStream_t stream)
{
    const float* x      = (const float*)d_in[0];
    const float* w_head = (const float*)d_in[1];
    const float* b_head = (const float*)d_in[2];
    const float* w_h1a  = (const float*)d_in[3];
    const float* b_h1a  = (const float*)d_in[4];
    const float* w_h1b  = (const float*)d_in[5];
    const float* b_h1b  = (const float*)d_in[6];
    const float* du1_w1 = (const float*)d_in[7];
    const float* du1_b1 = (const float*)d_in[8];
    const float* du1_w2 = (const float*)d_in[9];
    const float* du1_b2 = (const float*)d_in[10];
    const float* w_h2a  = (const float*)d_in[11];
    const float* b_h2a  = (const float*)d_in[12];
    const float* w_h2b  = (const float*)d_in[13];
    const float* b_h2b  = (const float*)d_in[14];
    const float* du2_w1 = (const float*)d_in[15];
    const float* du2_b1 = (const float*)d_in[16];
    const float* du2_w2 = (const float*)d_in[17];
    const float* du2_b2 = (const float*)d_in[18];
    const float* w_tail = (const float*)d_in[19];
    const float* b_tail = (const float*)d_in[20];
    const float* kern   = (const float*)d_in[21];
    float* out = (float*)d_out;

    unsigned short* fb0  = (unsigned short*)d_ws;        // 16,777,216 elems
    unsigned short* fb1  = fb0 + 16777216;
    unsigned short* wgtb = fb1 + 16777216;               // 8*16384*80
    unsigned short* wt1  = wgtb + 10485760;              // 9*4*128*32 = 147456 each
    unsigned short* wt2  = wt1 + 147456;
    unsigned short* wt3  = wt2 + 147456;
    unsigned short* wt4  = wt3 + 147456;
    unsigned short* wtt  = wt4 + 147456;                 // 9*4*80*32 = 92160
    unsigned short* wsa  = wtt + 92160;                  // 8x scaled h2a weights
    unsigned short* wst  = wsa + 8 * 147456;             // 8x scaled tail weights
    float* meanb  = (float*)(wst + 8 * 92160);
    float* scaleb = meanb + 1024;

    dim3 blk(256);
    wtrans<<<576, blk, 0, stream>>>(w_h1a, wt1, 128, 128);
    wtrans<<<576, blk, 0, stream>>>(w_h1b, wt2, 128, 128);
    wtrans<<<576, blk, 0, stream>>>(w_h2a, wt3, 128, 128);
    wtrans<<<576, blk, 0, stream>>>(w_h2b, wt4, 128, 128);
    wtrans<<<360, blk, 0, stream>>>(w_tail, wtt, 72, 80);

    head_conv<<<dim3(16, 16, 8), blk, 0, stream>>>(x, w_head, b_head, fb0);

    dim3 cgrid(64, 8);
    conv_mfma<8><<<cgrid, blk, 0, stream>>>(fb0, wt1, 0, b_h1a, fb1, 128, 128, 1);
    conv_mfma<8><<<cgrid, blk, 0, stream>>>(fb1, wt2, 0, b_h1b, fb0, 128, 128, 1);

    hipMemsetAsync(meanb, 0, 4096, stream);
    mean_nhwc<<<256, blk, 0, stream>>>(fb0, meanb);
    se_kernel<<<8, 128, 0, stream>>>(meanb, du1_w1, du1_b1, du1_w2, du1_b2, scaleb);
    wscale8<<<dim3(576, 8), blk, 0, stream>>>(wt3, scaleb, wsa, 128);

    conv_mfma<8><<<cgrid, blk, 0, stream>>>(fb0, wsa, 147456, b_h2a, fb1, 128, 128, 1);
    conv_mfma<8><<<cgrid, blk, 0, stream>>>(fb1, wt4, 0, b_h2b, fb0, 128, 128, 1);

    hipMemsetAsync(meanb, 0, 4096, stream);
    mean_nhwc<<<256, blk, 0, stream>>>(fb0, meanb);
    se_kernel<<<8, 128, 0, stream>>>(meanb, du2_w1, du2_b1, du2_w2, du2_b2, scaleb);
    wscale8<<<dim3(360, 8), blk, 0, stream>>>(wtt, scaleb, wst, 80);

    conv_mfma<5><<<cgrid, blk, 0, stream>>>(fb0, wst, 92160, b_tail, wgtb, 80, 72, 0);

    dynfilter<<<512, blk, 0, stream>>>(x, wgtb, kern, out);
}

// Round 5
// 427.643 us; speedup vs baseline: 11.5226x; 1.2320x over previous
//
#include <hip/hip_runtime.h>
#include <math.h>

// ---------------------------------------------------------------------------
// R5: mean_nhwc rewritten for coalescing (bf16x8, 1KB/wave contiguous, LDS
// reduce, 1 atomic/ch/block): was 62us @ 271 GB/s, pure latency-bound.
// Everything else unchanged from R4 (conv lm=4, dynfilter LDS-staged wgt,
// SE folded into per-batch scaled weights).
// ---------------------------------------------------------------------------

typedef __attribute__((ext_vector_type(8))) short bf16x8;
typedef __attribute__((ext_vector_type(4))) float f32x4;

__device__ inline float bf2f(unsigned short u) {
    unsigned v = ((unsigned)u) << 16;
    return __builtin_bit_cast(float, v);
}
__device__ inline unsigned short f2bf(float f) {
    unsigned u = __builtin_bit_cast(unsigned, f);
    u += 0x7FFF + ((u >> 16) & 1);   // RNE
    return (unsigned short)(u >> 16);
}

// ---------------- head conv: fp32 NCHW (Cin=3) -> NHWC bf16 (C=128) ---------
__global__ __launch_bounds__(256) void head_conv(
    const float* __restrict__ x, const float* __restrict__ w,
    const float* __restrict__ bias, unsigned short* __restrict__ out)
{
    __shared__ float wlds[216];          // [ci][tap][co8]
    __shared__ float tile[3][34 * 34];
    const int tid = threadIdx.x, cog = blockIdx.y, b = blockIdx.z;
    const int tile_y = (blockIdx.x >> 2) * 32, tile_x = (blockIdx.x & 3) * 32;

    if (tid < 216) {
        int co = tid & 7, rest = tid >> 3, tap = rest % 9, ci = rest / 9;
        wlds[tid] = w[((cog * 8 + co) * 3 + ci) * 9 + tap];
    }
    for (int idx = tid; idx < 3 * 34 * 34; idx += 256) {
        int ci = idx / 1156, rem = idx - ci * 1156;
        int r = rem / 34, c = rem - r * 34;
        int gy = tile_y - 1 + r, gx = tile_x - 1 + c;
        float v = 0.f;
        if ((unsigned)gy < 128u && (unsigned)gx < 128u)
            v = x[(((size_t)(b * 3 + ci)) << 14) + (gy << 7) + gx];
        tile[ci][rem] = v;
    }
    __syncthreads();

    const int ty = tid >> 4, tx = tid & 15, py = ty * 2;
    float acc[2][2][8];
    #pragma unroll
    for (int r = 0; r < 2; ++r)
        #pragma unroll
        for (int h = 0; h < 2; ++h)
            #pragma unroll
            for (int co = 0; co < 8; ++co) acc[r][h][co] = 0.f;

    #pragma unroll
    for (int ci = 0; ci < 3; ++ci) {
        #pragma unroll
        for (int ky = 0; ky < 3; ++ky) {
            #pragma unroll
            for (int kx = 0; kx < 3; ++kx) {
                const float* wp = wlds + (ci * 9 + ky * 3 + kx) * 8;
                float i00 = tile[ci][(py + ky) * 34 + tx + kx];
                float i01 = tile[ci][(py + ky) * 34 + tx + 16 + kx];
                float i10 = tile[ci][(py + 1 + ky) * 34 + tx + kx];
                float i11 = tile[ci][(py + 1 + ky) * 34 + tx + 16 + kx];
                #pragma unroll
                for (int co = 0; co < 8; ++co) {
                    float wv = wp[co];
                    acc[0][0][co] += i00 * wv;
                    acc[0][1][co] += i01 * wv;
                    acc[1][0][co] += i10 * wv;
                    acc[1][1][co] += i11 * wv;
                }
            }
        }
    }

    #pragma unroll
    for (int r = 0; r < 2; ++r) {
        #pragma unroll
        for (int h = 0; h < 2; ++h) {
            int gy = tile_y + py + r, gx = tile_x + tx + h * 16;
            bf16x8 pv;
            #pragma unroll
            for (int co = 0; co < 8; ++co)
                pv[co] = (short)f2bf(acc[r][h][co] + bias[cog * 8 + co]);
            *(bf16x8*)(out + (((((size_t)b << 14) + gy * 128 + gx)) << 7) + cog * 8) = pv;
        }
    }
}

// ---------------- main conv: implicit GEMM, bf16 MFMA -----------------------
template <int NT>
__global__ __launch_bounds__(256, 2) void conv_mfma(
    const unsigned short* __restrict__ in, const unsigned short* __restrict__ wT,
    size_t wstride, const float* __restrict__ bias, unsigned short* __restrict__ out,
    int Coutp, int Cout, int relu)
{
    __shared__ unsigned short lds[324 * 72];  // 18x18 px, 64 ch + 8 pad (144 B/px)
    const int tid = threadIdx.x;
    const int b = blockIdx.y;
    const int row0 = (blockIdx.x >> 3) << 4;
    const int col0 = (blockIdx.x & 7) << 4;
    const int l = tid & 63, wv = tid >> 6;
    const int li = l & 15, lq = l >> 4;
    const size_t inb = ((size_t)b) << 14;
    const unsigned short* wbase = wT + (size_t)b * wstride;

    f32x4 acc[4][NT];
    #pragma unroll
    for (int lm = 0; lm < 4; ++lm)
        #pragma unroll
        for (int nt = 0; nt < NT; ++nt)
            acc[lm][nt] = (f32x4){0.f, 0.f, 0.f, 0.f};

    #pragma unroll 1
    for (int half = 0; half < 2; ++half) {
        __syncthreads();
        for (int u = tid; u < 2592; u += 256) {   // 324 px * 8 parts (64 ch)
            int px = u >> 3, part = u & 7;
            int hr = px / 18, hc = px - hr * 18;
            int gy = row0 - 1 + hr, gx = col0 - 1 + hc;
            bf16x8 v = {0, 0, 0, 0, 0, 0, 0, 0};
            if ((unsigned)gy < 128u && (unsigned)gx < 128u)
                v = *(const bf16x8*)(in + ((inb + (gy << 7) + gx) << 7) + half * 64 + part * 8);
            *(bf16x8*)(lds + px * 72 + part * 8) = v;
        }
        __syncthreads();

        auto loadB = [&](bf16x8 (&dst)[NT], int s) {
            int tap = s >> 1, kcl = s & 1;
            const unsigned short* p = wbase +
                (size_t)(tap * 4 + half * 2 + kcl) * (Coutp * 32) + li * 32 + lq * 8;
            #pragma unroll
            for (int nt = 0; nt < NT; ++nt)
                dst[nt] = *(const bf16x8*)(p + nt * 512);
        };
        auto compute = [&](bf16x8 (&bf)[NT], int s) {
            int tap = s >> 1, kcl = s & 1;
            int ky = tap / 3, kx = tap - ky * 3;
            int coff = kcl * 32 + lq * 8;
            #pragma unroll
            for (int lm = 0; lm < 4; ++lm) {
                bf16x8 af = *(const bf16x8*)(
                    lds + ((wv * 4 + lm + ky) * 18 + li + kx) * 72 + coff);
                #pragma unroll
                for (int nt = 0; nt < NT; ++nt)
                    acc[lm][nt] = __builtin_amdgcn_mfma_f32_16x16x32_bf16(
                        af, bf[nt], acc[lm][nt], 0, 0, 0);
            }
        };

        bf16x8 bufA[NT], bufB[NT];
        loadB(bufA, 0);
        #pragma unroll 1
        for (int it = 0; it < 18; it += 2) {
            loadB(bufB, it + 1);
            compute(bufA, it);
            if (it + 2 < 18) loadB(bufA, it + 2);
            compute(bufB, it + 1);
        }
    }

    float bv[NT];
    #pragma unroll
    for (int nt = 0; nt < NT; ++nt) {
        int co = nt * 16 + li;
        bv[nt] = (co < Cout) ? bias[co] : 0.f;
    }
    #pragma unroll
    for (int lm = 0; lm < 4; ++lm) {
        int row = row0 + wv * 4 + lm;
        #pragma unroll
        for (int r = 0; r < 4; ++r) {
            int col = col0 + lq * 4 + r;
            size_t pbase = (inb + row * 128 + col) * (size_t)Coutp;
            #pragma unroll
            for (int nt = 0; nt < NT; ++nt) {
                float v = acc[lm][nt][r] + bv[nt];
                if (relu) v = fmaxf(v, 0.f);
                out[pbase + nt * 16 + li] = f2bf(v);
            }
        }
    }
}

// ---- weight transform: [Co][128][3][3] f32 -> [tap*4+kc][Coutp][32] bf16 ---
__global__ __launch_bounds__(256) void wtrans(
    const float* __restrict__ w, unsigned short* __restrict__ wT, int Co, int Coutp)
{
    int idx = blockIdx.x * 256 + threadIdx.x;
    if (idx >= 9 * 4 * Coutp * 32) return;
    int ch = idx & 31;
    int rest = idx >> 5;          // (tap*4+kc)*Coutp + co
    int co = rest % Coutp;
    int slice = rest / Coutp;
    int kc = slice & 3, tap = slice >> 2;
    float v = (co < Co) ? w[((size_t)(co * 128 + kc * 32 + ch)) * 9 + tap] : 0.f;
    wT[idx] = f2bf(v);
}

// ---- per-batch SE-scaled weight copies: out[b][...] = wT[...] * s[b][ci] ---
__global__ __launch_bounds__(256) void wscale8(
    const unsigned short* __restrict__ wT, const float* __restrict__ scale,
    unsigned short* __restrict__ out, int Coutp)
{
    int r = blockIdx.x * 256 + threadIdx.x;
    int b = blockIdx.y;
    int ch = r & 31;
    int slice = (r >> 5) / Coutp;
    int kc = slice & 3;
    float s = scale[b * 128 + kc * 32 + ch];
    out[(size_t)b * (9 * 4 * Coutp * 32) + r] = f2bf(bf2f(wT[r]) * s);
}

// ---------------- SE mean: coalesced bf16x8, LDS reduce, 1 atomic/ch --------
// grid (64, 8): 64 slabs of 256 px per batch. Wave load = 4 px * 128 ch = 1KB.
__global__ __launch_bounds__(256) void mean_nhwc(
    const unsigned short* __restrict__ f, float* __restrict__ meanb)
{
    const int b = blockIdx.y, slab = blockIdx.x;
    const int p = threadIdx.x >> 4, g = threadIdx.x & 15;
    const size_t base = ((size_t)b << 14) + slab * 256;

    float s[8] = {0.f, 0.f, 0.f, 0.f, 0.f, 0.f, 0.f, 0.f};
    #pragma unroll
    for (int i = 0; i < 16; ++i) {
        bf16x8 v = *(const bf16x8*)(f + ((base + p + i * 16) << 7) + g * 8);
        #pragma unroll
        for (int j = 0; j < 8; ++j) s[j] += bf2f((unsigned short)v[j]);
    }

    __shared__ float tmp[16][16][8];   // [p][g][j]
    #pragma unroll
    for (int j = 0; j < 8; ++j) tmp[p][g][j] = s[j];
    __syncthreads();
    if (threadIdx.x < 128) {
        int ch = threadIdx.x;
        float t = 0.f;
        #pragma unroll
        for (int pp = 0; pp < 16; ++pp) t += tmp[pp][ch >> 3][ch & 7];
        atomicAdd(&meanb[b * 128 + ch], t);
    }
}

__global__ __launch_bounds__(128) void se_kernel(
    const float* __restrict__ meanb, const float* __restrict__ w1,
    const float* __restrict__ b1, const float* __restrict__ w2,
    const float* __restrict__ b2, float* __restrict__ scale)
{
    const int b = blockIdx.x, c = threadIdx.x;
    __shared__ float h1[8];
    if (c < 8) {
        float s = 0.f;
        for (int j = 0; j < 128; ++j) s += w1[c * 128 + j] * meanb[b * 128 + j];
        h1[c] = fmaxf(s * (1.f / 16384.f) + b1[c], 0.f);
    }
    __syncthreads();
    float s = b2[c];
    #pragma unroll
    for (int j = 0; j < 8; ++j) s += w2[c * 8 + j] * h1[j];
    scale[b * 128 + c] = 1.f / (1.f + expf(-s));
}

// ---------------- dynamic filter: wgt staged via LDS for coalescing ---------
__global__ __launch_bounds__(256) void dynfilter(
    const float* __restrict__ x, const unsigned short* __restrict__ wgt,
    const float* __restrict__ kern, float* __restrict__ out)
{
    __shared__ unsigned short wl[256 * 88];   // 256 px, 80 wgt + 8 pad (176 B/px)
    const int blk = blockIdx.x;               // 512 blocks
    const int b = blk >> 6;
    const int px0 = (blk & 63) << 8;

    const unsigned short* src = wgt + ((size_t)b * 16384 + px0) * 80;
    for (int u = threadIdx.x; u < 2560; u += 256) {   // coalesced 16B units
        int px = u / 10, k8 = u - px * 10;
        *(bf16x8*)(wl + px * 88 + k8 * 8) = *(const bf16x8*)(src + u * 8);
    }
    __syncthreads();

    const int pix = px0 + threadIdx.x;
    const int h = pix >> 7, w = pix & 127;
    const unsigned short* rowp = wl + threadIdx.x * 88;

    float e[25];
    #pragma unroll
    for (int i = 0; i < 25; ++i) e[i] = 0.f;
    #pragma unroll
    for (int u8 = 0; u8 < 9; ++u8) {          // 72 = 9*8 exactly
        bf16x8 wv8 = *(const bf16x8*)(rowp + u8 * 8);
        #pragma unroll
        for (int j = 0; j < 8; ++j) {
            float wk = bf2f((unsigned short)wv8[j]);
            const float* kp = kern + (u8 * 8 + j) * 25;   // lane-uniform -> s_load
            #pragma unroll
            for (int i = 0; i < 25; ++i) e[i] += wk * kp[i];
        }
    }

    int yy[5], xx[5];
    #pragma unroll
    for (int d = 0; d < 5; ++d) {
        int y = h - 2 + d;
        yy[d] = y < 0 ? -y : (y > 127 ? 254 - y : y);
        int xv = w - 2 + d;
        xx[d] = xv < 0 ? -xv : (xv > 127 ? 254 - xv : xv);
    }

    #pragma unroll
    for (int c = 0; c < 3; ++c) {
        const float* xc = x + ((size_t)(b * 3 + c) << 14);
        float s = 0.f;
        #pragma unroll
        for (int dy = 0; dy < 5; ++dy)
            #pragma unroll
            for (int dx = 0; dx < 5; ++dx)
                s += e[dy * 5 + dx] * xc[yy[dy] * 128 + xx[dx]];
        out[((size_t)(b * 3 + c) << 14) + pix] = s;
    }
}

// ---------------------------------------------------------------------------
extern "C" void kernel_launch(void* const* d_in, const int* in_sizes, int n_in,
                              void* d_out, int out_size, void* d_ws, size_t ws_size,
                              hipStream_t stream)
{
    const float* x      = (const float*)d_in[0];
    const float* w_head = (const float*)d_in[1];
    const float* b_head = (const float*)d_in[2];
    const float* w_h1a  = (const float*)d_in[3];
    const float* b_h1a  = (const float*)d_in[4];
    const float* w_h1b  = (const float*)d_in[5];
    const float* b_h1b  = (const float*)d_in[6];
    const float* du1_w1 = (const float*)d_in[7];
    const float* du1_b1 = (const float*)d_in[8];
    const float* du1_w2 = (const float*)d_in[9];
    const float* du1_b2 = (const float*)d_in[10];
    const float* w_h2a  = (const float*)d_in[11];
    const float* b_h2a  = (const float*)d_in[12];
    const float* w_h2b  = (const float*)d_in[13];
    const float* b_h2b  = (const float*)d_in[14];
    const float* du2_w1 = (const float*)d_in[15];
    const float* du2_b1 = (const float*)d_in[16];
    const float* du2_w2 = (const float*)d_in[17];
    const float* du2_b2 = (const float*)d_in[18];
    const float* w_tail = (const float*)d_in[19];
    const float* b_tail = (const float*)d_in[20];
    const float* kern   = (const float*)d_in[21];
    float* out = (float*)d_out;

    unsigned short* fb0  = (unsigned short*)d_ws;        // 16,777,216 elems
    unsigned short* fb1  = fb0 + 16777216;
    unsigned short* wgtb = fb1 + 16777216;               // 8*16384*80
    unsigned short* wt1  = wgtb + 10485760;              // 9*4*128*32 = 147456 each
    unsigned short* wt2  = wt1 + 147456;
    unsigned short* wt3  = wt2 + 147456;
    unsigned short* wt4  = wt3 + 147456;
    unsigned short* wtt  = wt4 + 147456;                 // 9*4*80*32 = 92160
    unsigned short* wsa  = wtt + 92160;                  // 8x scaled h2a weights
    unsigned short* wst  = wsa + 8 * 147456;             // 8x scaled tail weights
    float* meanb  = (float*)(wst + 8 * 92160);
    float* scaleb = meanb + 1024;

    dim3 blk(256);
    wtrans<<<576, blk, 0, stream>>>(w_h1a, wt1, 128, 128);
    wtrans<<<576, blk, 0, stream>>>(w_h1b, wt2, 128, 128);
    wtrans<<<576, blk, 0, stream>>>(w_h2a, wt3, 128, 128);
    wtrans<<<576, blk, 0, stream>>>(w_h2b, wt4, 128, 128);
    wtrans<<<360, blk, 0, stream>>>(w_tail, wtt, 72, 80);

    head_conv<<<dim3(16, 16, 8), blk, 0, stream>>>(x, w_head, b_head, fb0);

    dim3 cgrid(64, 8);
    conv_mfma<8><<<cgrid, blk, 0, stream>>>(fb0, wt1, 0, b_h1a, fb1, 128, 128, 1);
    conv_mfma<8><<<cgrid, blk, 0, stream>>>(fb1, wt2, 0, b_h1b, fb0, 128, 128, 1);

    hipMemsetAsync(meanb, 0, 4096, stream);
    mean_nhwc<<<dim3(64, 8), blk, 0, stream>>>(fb0, meanb);
    se_kernel<<<8, 128, 0, stream>>>(meanb, du1_w1, du1_b1, du1_w2, du1_b2, scaleb);
    wscale8<<<dim3(576, 8), blk, 0, stream>>>(wt3, scaleb, wsa, 128);

    conv_mfma<8><<<cgrid, blk, 0, stream>>>(fb0, wsa, 147456, b_h2a, fb1, 128, 128, 1);
    conv_mfma<8><<<cgrid, blk, 0, stream>>>(fb1, wt4, 0, b_h2b, fb0, 128, 128, 1);

    hipMemsetAsync(meanb, 0, 4096, stream);
    mean_nhwc<<<dim3(64, 8), blk, 0, stream>>>(fb0, meanb);
    se_kernel<<<8, 128, 0, stream>>>(meanb, du2_w1, du2_b1, du2_w2, du2_b2, scaleb);
    wscale8<<<dim3(360, 8), blk, 0, stream>>>(wtt, scaleb, wst, 80);

    conv_mfma<5><<<cgrid, blk, 0, stream>>>(fb0, wst, 92160, b_tail, wgtb, 80, 72, 0);

    dynfilter<<<512, blk, 0, stream>>>(x, wgtb, kern, out);
}

// Round 6
// 375.880 us; speedup vs baseline: 13.1095x; 1.1377x over previous
//
#include <hip/hip_runtime.h>
#include <math.h>

// ---------------------------------------------------------------------------
// R6: conv_mfma wave re-split lm=8 x ntw=4 (N split across wave pairs):
// B L2-traffic per block 1.15MB -> 576KB (was L2-BW-bound at 26% MfmaUtil).
// Tail conv (Coutp=80) keeps lm=4 full-N shape via NSPLIT=0 template flag.
// Rest unchanged from R5.
// ---------------------------------------------------------------------------

typedef __attribute__((ext_vector_type(8))) short bf16x8;
typedef __attribute__((ext_vector_type(4))) float f32x4;

__device__ inline float bf2f(unsigned short u) {
    unsigned v = ((unsigned)u) << 16;
    return __builtin_bit_cast(float, v);
}
__device__ inline unsigned short f2bf(float f) {
    unsigned u = __builtin_bit_cast(unsigned, f);
    u += 0x7FFF + ((u >> 16) & 1);   // RNE
    return (unsigned short)(u >> 16);
}

// ---------------- head conv: fp32 NCHW (Cin=3) -> NHWC bf16 (C=128) ---------
__global__ __launch_bounds__(256) void head_conv(
    const float* __restrict__ x, const float* __restrict__ w,
    const float* __restrict__ bias, unsigned short* __restrict__ out)
{
    __shared__ float wlds[216];          // [ci][tap][co8]
    __shared__ float tile[3][34 * 34];
    const int tid = threadIdx.x, cog = blockIdx.y, b = blockIdx.z;
    const int tile_y = (blockIdx.x >> 2) * 32, tile_x = (blockIdx.x & 3) * 32;

    if (tid < 216) {
        int co = tid & 7, rest = tid >> 3, tap = rest % 9, ci = rest / 9;
        wlds[tid] = w[((cog * 8 + co) * 3 + ci) * 9 + tap];
    }
    for (int idx = tid; idx < 3 * 34 * 34; idx += 256) {
        int ci = idx / 1156, rem = idx - ci * 1156;
        int r = rem / 34, c = rem - r * 34;
        int gy = tile_y - 1 + r, gx = tile_x - 1 + c;
        float v = 0.f;
        if ((unsigned)gy < 128u && (unsigned)gx < 128u)
            v = x[(((size_t)(b * 3 + ci)) << 14) + (gy << 7) + gx];
        tile[ci][rem] = v;
    }
    __syncthreads();

    const int ty = tid >> 4, tx = tid & 15, py = ty * 2;
    float acc[2][2][8];
    #pragma unroll
    for (int r = 0; r < 2; ++r)
        #pragma unroll
        for (int h = 0; h < 2; ++h)
            #pragma unroll
            for (int co = 0; co < 8; ++co) acc[r][h][co] = 0.f;

    #pragma unroll
    for (int ci = 0; ci < 3; ++ci) {
        #pragma unroll
        for (int ky = 0; ky < 3; ++ky) {
            #pragma unroll
            for (int kx = 0; kx < 3; ++kx) {
                const float* wp = wlds + (ci * 9 + ky * 3 + kx) * 8;
                float i00 = tile[ci][(py + ky) * 34 + tx + kx];
                float i01 = tile[ci][(py + ky) * 34 + tx + 16 + kx];
                float i10 = tile[ci][(py + 1 + ky) * 34 + tx + kx];
                float i11 = tile[ci][(py + 1 + ky) * 34 + tx + 16 + kx];
                #pragma unroll
                for (int co = 0; co < 8; ++co) {
                    float wv = wp[co];
                    acc[0][0][co] += i00 * wv;
                    acc[0][1][co] += i01 * wv;
                    acc[1][0][co] += i10 * wv;
                    acc[1][1][co] += i11 * wv;
                }
            }
        }
    }

    #pragma unroll
    for (int r = 0; r < 2; ++r) {
        #pragma unroll
        for (int h = 0; h < 2; ++h) {
            int gy = tile_y + py + r, gx = tile_x + tx + h * 16;
            bf16x8 pv;
            #pragma unroll
            for (int co = 0; co < 8; ++co)
                pv[co] = (short)f2bf(acc[r][h][co] + bias[cog * 8 + co]);
            *(bf16x8*)(out + (((((size_t)b << 14) + gy * 128 + gx)) << 7) + cog * 8) = pv;
        }
    }
}

// ---------------- main conv: implicit GEMM, bf16 MFMA -----------------------
// Wave covers LM m-tiles (LM*16 px... LM rows of 16) x NTW n-tiles (NTW*16 co).
// NSPLIT=1: m_base=(wv>>1)*LM, n_base=(wv&1)*NTW (4 waves tile 16 rows x 2*NTW).
// NSPLIT=0: m_base=wv*LM, n_base=0 (R4 shape, for odd Coutp/16).
template <int LM, int NTW, int NSPLIT>
__global__ __launch_bounds__(256, 2) void conv_mfma(
    const unsigned short* __restrict__ in, const unsigned short* __restrict__ wT,
    size_t wstride, const float* __restrict__ bias, unsigned short* __restrict__ out,
    int Coutp, int Cout, int relu)
{
    __shared__ unsigned short lds[324 * 72];  // 18x18 px, 64 ch + 8 pad (144 B/px)
    const int tid = threadIdx.x;
    const int b = blockIdx.y;
    const int row0 = (blockIdx.x >> 3) << 4;
    const int col0 = (blockIdx.x & 7) << 4;
    const int l = tid & 63, wv = tid >> 6;
    const int li = l & 15, lq = l >> 4;
    const int m_base = NSPLIT ? (wv >> 1) * LM : wv * LM;
    const int n_base = NSPLIT ? (wv & 1) * NTW : 0;
    const size_t inb = ((size_t)b) << 14;
    const unsigned short* wbase = wT + (size_t)b * wstride;

    f32x4 acc[LM][NTW];
    #pragma unroll
    for (int lm = 0; lm < LM; ++lm)
        #pragma unroll
        for (int nt = 0; nt < NTW; ++nt)
            acc[lm][nt] = (f32x4){0.f, 0.f, 0.f, 0.f};

    #pragma unroll 1
    for (int half = 0; half < 2; ++half) {
        __syncthreads();
        for (int u = tid; u < 2592; u += 256) {   // 324 px * 8 parts (64 ch)
            int px = u >> 3, part = u & 7;
            int hr = px / 18, hc = px - hr * 18;
            int gy = row0 - 1 + hr, gx = col0 - 1 + hc;
            bf16x8 v = {0, 0, 0, 0, 0, 0, 0, 0};
            if ((unsigned)gy < 128u && (unsigned)gx < 128u)
                v = *(const bf16x8*)(in + ((inb + (gy << 7) + gx) << 7) + half * 64 + part * 8);
            *(bf16x8*)(lds + px * 72 + part * 8) = v;
        }
        __syncthreads();

        auto loadB = [&](bf16x8 (&dst)[NTW], int s) {
            int tap = s >> 1, kcl = s & 1;
            const unsigned short* p = wbase +
                (size_t)(tap * 4 + half * 2 + kcl) * (Coutp * 32) +
                (n_base * 16 + li) * 32 + lq * 8;
            #pragma unroll
            for (int nt = 0; nt < NTW; ++nt)
                dst[nt] = *(const bf16x8*)(p + nt * 512);
        };
        auto compute = [&](bf16x8 (&bf)[NTW], int s) {
            int tap = s >> 1, kcl = s & 1;
            int ky = tap / 3, kx = tap - ky * 3;
            int coff = kcl * 32 + lq * 8;
            #pragma unroll
            for (int lm = 0; lm < LM; ++lm) {
                bf16x8 af = *(const bf16x8*)(
                    lds + ((m_base + lm + ky) * 18 + li + kx) * 72 + coff);
                #pragma unroll
                for (int nt = 0; nt < NTW; ++nt)
                    acc[lm][nt] = __builtin_amdgcn_mfma_f32_16x16x32_bf16(
                        af, bf[nt], acc[lm][nt], 0, 0, 0);
            }
        };

        bf16x8 bufA[NTW], bufB[NTW];
        loadB(bufA, 0);
        #pragma unroll 1
        for (int it = 0; it < 18; it += 2) {
            loadB(bufB, it + 1);
            compute(bufA, it);
            if (it + 2 < 18) loadB(bufA, it + 2);
            compute(bufB, it + 1);
        }
    }

    float bv[NTW];
    #pragma unroll
    for (int nt = 0; nt < NTW; ++nt) {
        int co = (n_base + nt) * 16 + li;
        bv[nt] = (co < Cout) ? bias[co] : 0.f;
    }
    #pragma unroll
    for (int lm = 0; lm < LM; ++lm) {
        int row = row0 + m_base + lm;
        #pragma unroll
        for (int r = 0; r < 4; ++r) {
            int col = col0 + lq * 4 + r;
            size_t pbase = (inb + row * 128 + col) * (size_t)Coutp;
            #pragma unroll
            for (int nt = 0; nt < NTW; ++nt) {
                float v = acc[lm][nt][r] + bv[nt];
                if (relu) v = fmaxf(v, 0.f);
                out[pbase + (n_base + nt) * 16 + li] = f2bf(v);
            }
        }
    }
}

// ---- weight transform: [Co][128][3][3] f32 -> [tap*4+kc][Coutp][32] bf16 ---
__global__ __launch_bounds__(256) void wtrans(
    const float* __restrict__ w, unsigned short* __restrict__ wT, int Co, int Coutp)
{
    int idx = blockIdx.x * 256 + threadIdx.x;
    if (idx >= 9 * 4 * Coutp * 32) return;
    int ch = idx & 31;
    int rest = idx >> 5;          // (tap*4+kc)*Coutp + co
    int co = rest % Coutp;
    int slice = rest / Coutp;
    int kc = slice & 3, tap = slice >> 2;
    float v = (co < Co) ? w[((size_t)(co * 128 + kc * 32 + ch)) * 9 + tap] : 0.f;
    wT[idx] = f2bf(v);
}

// ---- per-batch SE-scaled weight copies: out[b][...] = wT[...] * s[b][ci] ---
__global__ __launch_bounds__(256) void wscale8(
    const unsigned short* __restrict__ wT, const float* __restrict__ scale,
    unsigned short* __restrict__ out, int Coutp)
{
    int r = blockIdx.x * 256 + threadIdx.x;
    int b = blockIdx.y;
    int ch = r & 31;
    int slice = (r >> 5) / Coutp;
    int kc = slice & 3;
    float s = scale[b * 128 + kc * 32 + ch];
    out[(size_t)b * (9 * 4 * Coutp * 32) + r] = f2bf(bf2f(wT[r]) * s);
}

// ---------------- SE mean: coalesced bf16x8, LDS reduce, 1 atomic/ch --------
__global__ __launch_bounds__(256) void mean_nhwc(
    const unsigned short* __restrict__ f, float* __restrict__ meanb)
{
    const int b = blockIdx.y, slab = blockIdx.x;
    const int p = threadIdx.x >> 4, g = threadIdx.x & 15;
    const size_t base = ((size_t)b << 14) + slab * 256;

    float s[8] = {0.f, 0.f, 0.f, 0.f, 0.f, 0.f, 0.f, 0.f};
    #pragma unroll
    for (int i = 0; i < 16; ++i) {
        bf16x8 v = *(const bf16x8*)(f + ((base + p + i * 16) << 7) + g * 8);
        #pragma unroll
        for (int j = 0; j < 8; ++j) s[j] += bf2f((unsigned short)v[j]);
    }

    __shared__ float tmp[16][16][8];   // [p][g][j]
    #pragma unroll
    for (int j = 0; j < 8; ++j) tmp[p][g][j] = s[j];
    __syncthreads();
    if (threadIdx.x < 128) {
        int ch = threadIdx.x;
        float t = 0.f;
        #pragma unroll
        for (int pp = 0; pp < 16; ++pp) t += tmp[pp][ch >> 3][ch & 7];
        atomicAdd(&meanb[b * 128 + ch], t);
    }
}

__global__ __launch_bounds__(128) void se_kernel(
    const float* __restrict__ meanb, const float* __restrict__ w1,
    const float* __restrict__ b1, const float* __restrict__ w2,
    const float* __restrict__ b2, float* __restrict__ scale)
{
    const int b = blockIdx.x, c = threadIdx.x;
    __shared__ float h1[8];
    if (c < 8) {
        float s = 0.f;
        for (int j = 0; j < 128; ++j) s += w1[c * 128 + j] * meanb[b * 128 + j];
        h1[c] = fmaxf(s * (1.f / 16384.f) + b1[c], 0.f);
    }
    __syncthreads();
    float s = b2[c];
    #pragma unroll
    for (int j = 0; j < 8; ++j) s += w2[c * 8 + j] * h1[j];
    scale[b * 128 + c] = 1.f / (1.f + expf(-s));
}

// ---------------- dynamic filter: wgt staged via LDS for coalescing ---------
__global__ __launch_bounds__(256) void dynfilter(
    const float* __restrict__ x, const unsigned short* __restrict__ wgt,
    const float* __restrict__ kern, float* __restrict__ out)
{
    __shared__ unsigned short wl[256 * 88];   // 256 px, 80 wgt + 8 pad (176 B/px)
    const int blk = blockIdx.x;               // 512 blocks
    const int b = blk >> 6;
    const int px0 = (blk & 63) << 8;

    const unsigned short* src = wgt + ((size_t)b * 16384 + px0) * 80;
    for (int u = threadIdx.x; u < 2560; u += 256) {   // coalesced 16B units
        int px = u / 10, k8 = u - px * 10;
        *(bf16x8*)(wl + px * 88 + k8 * 8) = *(const bf16x8*)(src + u * 8);
    }
    __syncthreads();

    const int pix = px0 + threadIdx.x;
    const int h = pix >> 7, w = pix & 127;
    const unsigned short* rowp = wl + threadIdx.x * 88;

    float e[25];
    #pragma unroll
    for (int i = 0; i < 25; ++i) e[i] = 0.f;
    #pragma unroll
    for (int u8 = 0; u8 < 9; ++u8) {          // 72 = 9*8 exactly
        bf16x8 wv8 = *(const bf16x8*)(rowp + u8 * 8);
        #pragma unroll
        for (int j = 0; j < 8; ++j) {
            float wk = bf2f((unsigned short)wv8[j]);
            const float* kp = kern + (u8 * 8 + j) * 25;   // lane-uniform -> s_load
            #pragma unroll
            for (int i = 0; i < 25; ++i) e[i] += wk * kp[i];
        }
    }

    int yy[5], xx[5];
    #pragma unroll
    for (int d = 0; d < 5; ++d) {
        int y = h - 2 + d;
        yy[d] = y < 0 ? -y : (y > 127 ? 254 - y : y);
        int xv = w - 2 + d;
        xx[d] = xv < 0 ? -xv : (xv > 127 ? 254 - xv : xv);
    }

    #pragma unroll
    for (int c = 0; c < 3; ++c) {
        const float* xc = x + ((size_t)(b * 3 + c) << 14);
        float s = 0.f;
        #pragma unroll
        for (int dy = 0; dy < 5; ++dy)
            #pragma unroll
            for (int dx = 0; dx < 5; ++dx)
                s += e[dy * 5 + dx] * xc[yy[dy] * 128 + xx[dx]];
        out[((size_t)(b * 3 + c) << 14) + pix] = s;
    }
}

// ---------------------------------------------------------------------------
extern "C" void kernel_launch(void* const* d_in, const int* in_sizes, int n_in,
                              void* d_out, int out_size, void* d_ws, size_t ws_size,
                              hipStream_t stream)
{
    const float* x      = (const float*)d_in[0];
    const float* w_head = (const float*)d_in[1];
    const float* b_head = (const float*)d_in[2];
    const float* w_h1a  = (const float*)d_in[3];
    const float* b_h1a  = (const float*)d_in[4];
    const float* w_h1b  = (const float*)d_in[5];
    const float* b_h1b  = (const float*)d_in[6];
    const float* du1_w1 = (const float*)d_in[7];
    const float* du1_b1 = (const float*)d_in[8];
    const float* du1_w2 = (const float*)d_in[9];
    const float* du1_b2 = (const float*)d_in[10];
    const float* w_h2a  = (const float*)d_in[11];
    const float* b_h2a  = (const float*)d_in[12];
    const float* w_h2b  = (const float*)d_in[13];
    const float* b_h2b  = (const float*)d_in[14];
    const float* du2_w1 = (const float*)d_in[15];
    const float* du2_b1 = (const float*)d_in[16];
    const float* du2_w2 = (const float*)d_in[17];
    const float* du2_b2 = (const float*)d_in[18];
    const float* w_tail = (const float*)d_in[19];
    const float* b_tail = (const float*)d_in[20];
    const float* kern   = (const float*)d_in[21];
    float* out = (float*)d_out;

    unsigned short* fb0  = (unsigned short*)d_ws;        // 16,777,216 elems
    unsigned short* fb1  = fb0 + 16777216;
    unsigned short* wgtb = fb1 + 16777216;               // 8*16384*80
    unsigned short* wt1  = wgtb + 10485760;              // 9*4*128*32 = 147456 each
    unsigned short* wt2  = wt1 + 147456;
    unsigned short* wt3  = wt2 + 147456;
    unsigned short* wt4  = wt3 + 147456;
    unsigned short* wtt  = wt4 + 147456;                 // 9*4*80*32 = 92160
    unsigned short* wsa  = wtt + 92160;                  // 8x scaled h2a weights
    unsigned short* wst  = wsa + 8 * 147456;             // 8x scaled tail weights
    float* meanb  = (float*)(wst + 8 * 92160);
    float* scaleb = meanb + 1024;

    dim3 blk(256);
    wtrans<<<576, blk, 0, stream>>>(w_h1a, wt1, 128, 128);
    wtrans<<<576, blk, 0, stream>>>(w_h1b, wt2, 128, 128);
    wtrans<<<576, blk, 0, stream>>>(w_h2a, wt3, 128, 128);
    wtrans<<<576, blk, 0, stream>>>(w_h2b, wt4, 128, 128);
    wtrans<<<360, blk, 0, stream>>>(w_tail, wtt, 72, 80);

    head_conv<<<dim3(16, 16, 8), blk, 0, stream>>>(x, w_head, b_head, fb0);

    dim3 cgrid(64, 8);
    conv_mfma<8, 4, 1><<<cgrid, blk, 0, stream>>>(fb0, wt1, 0, b_h1a, fb1, 128, 128, 1);
    conv_mfma<8, 4, 1><<<cgrid, blk, 0, stream>>>(fb1, wt2, 0, b_h1b, fb0, 128, 128, 1);

    hipMemsetAsync(meanb, 0, 4096, stream);
    mean_nhwc<<<dim3(64, 8), blk, 0, stream>>>(fb0, meanb);
    se_kernel<<<8, 128, 0, stream>>>(meanb, du1_w1, du1_b1, du1_w2, du1_b2, scaleb);
    wscale8<<<dim3(576, 8), blk, 0, stream>>>(wt3, scaleb, wsa, 128);

    conv_mfma<8, 4, 1><<<cgrid, blk, 0, stream>>>(fb0, wsa, 147456, b_h2a, fb1, 128, 128, 1);
    conv_mfma<8, 4, 1><<<cgrid, blk, 0, stream>>>(fb1, wt4, 0, b_h2b, fb0, 128, 128, 1);

    hipMemsetAsync(meanb, 0, 4096, stream);
    mean_nhwc<<<dim3(64, 8), blk, 0, stream>>>(fb0, meanb);
    se_kernel<<<8, 128, 0, stream>>>(meanb, du2_w1, du2_b1, du2_w2, du2_b2, scaleb);
    wscale8<<<dim3(360, 8), blk, 0, stream>>>(wtt, scaleb, wst, 80);

    conv_mfma<4, 5, 0><<<cgrid, blk, 0, stream>>>(fb0, wst, 92160, b_tail, wgtb, 80, 72, 0);

    dynfilter<<<512, blk, 0, stream>>>(x, wgtb, kern, out);
}